// Round 5
// baseline (2527.337 us; speedup 1.0000x reference)
//
#include <hip/hip_runtime.h>

// EAM force with R-way replicated accumulators to break same-cache-line
// serialization of device-scope fp32 atomics at the cross-XCD coherence point.
//  K0: zero replica arrays
//  K1 (per pair): density interp -> atomic add into rho_rep[blockIdx%R]
//  K2: rho_final = sum_k rho_rep[k]
//  K3 (per pair): dF(rho_final) inline; coeff -> atomic add force_rep[blockIdx%R]
//  K4: forces = sum_k force_rep[k]
//
// ws layout (floats): [0,N) rho_final | [N, N+R*N) rho_reps | [.., +R*3N) force_reps
// R adaptive to ws_size (<=16). R==0 fallback = round-4 direct-atomic path.

#define EAM_BLOCK 256

__device__ __forceinline__ void atomic_add_f32(float* p, float v) {
    unsafeAtomicAdd(p, v);   // global_atomic_add_f32
}

__device__ __forceinline__ float interp_row(const float* __restrict__ row,
                                            int i0, int i1, float fr) {
    float a = row[i0];
    float b = row[i1];
    return a + fr * (b - a);
}

__device__ __forceinline__ float embed_dF(float rho, int t,
                                          const float* __restrict__ embed_tab,
                                          const float* __restrict__ rho_min_t,
                                          const float* __restrict__ inv_drho_t,
                                          int n_rho, float one_m_eps) {
    float rmin = rho_min_t[t];
    float invd = inv_drho_t[t];
    float hi = rmin + (float)(n_rho - 1) / invd * one_m_eps;
    float rc = fminf(fmaxf(rho, rmin), hi);
    float g  = (rc - rmin) * invd;
    int  g0  = (int)g;
    g0 = g0 < 0 ? 0 : (g0 > n_rho - 2 ? n_rho - 2 : g0);
    float gfr = g - (float)g0;
    const float* row = embed_tab + (size_t)t * n_rho;
    float e0 = row[g0];
    float e1 = row[g0 + 1];
    return e0 + gfr * (e1 - e0);
}

__device__ __forceinline__ void pair_geom(
    const float* __restrict__ pos, int i, int j,
    float inv_dr, float rclip,
    float& dx, float& dy, float& dz, float& r,
    int& i0, int& i1, float& fr, int n_r)
{
#pragma clang fp contract(off)
    float xi = pos[3 * i + 0], yi = pos[3 * i + 1], zi = pos[3 * i + 2];
    float xj = pos[3 * j + 0], yj = pos[3 * j + 1], zj = pos[3 * j + 2];
    dx = xj - xi; dy = yj - yi; dz = zj - zi;
    float s = dx * dx;
    s = s + dy * dy;
    s = s + dz * dz;
    s = s + 1e-12f;
    r = sqrtf(s);

    float rc = fminf(fmaxf(r, 0.0f), rclip);
    float f  = rc * inv_dr;
    i0 = (int)f;
    fr = f - (float)i0;
    i1 = min(i0 + 1, n_r - 1);
}

__global__ void eam_zero4_kernel(float4* __restrict__ p, long long n4) {
    long long idx = (long long)blockIdx.x * blockDim.x + threadIdx.x;
    long long stride = (long long)gridDim.x * blockDim.x;
    for (; idx < n4; idx += stride)
        p[idx] = make_float4(0.f, 0.f, 0.f, 0.f);
}

__global__ void eam_zero_kernel(float* __restrict__ rho,
                                float* __restrict__ forces, int N) {
    int idx = blockIdx.x * blockDim.x + threadIdx.x;
    if (idx < N) rho[idx] = 0.0f;
    if (idx < 3 * N) forces[idx] = 0.0f;
}

__global__ void eam_density_kernel(
    const int* __restrict__ edge_i, const int* __restrict__ edge_j,
    const int* __restrict__ types, const float* __restrict__ pos,
    const float* __restrict__ dens_tab, int n_r, float inv_dr, float rclip,
    float* __restrict__ rho_reps, int R, int N, int P)
{
    int p = blockIdx.x * blockDim.x + threadIdx.x;
    if (p >= P) return;

    float* rho = rho_reps + (size_t)(blockIdx.x % R) * N;

    int i = edge_i[p];
    int j = edge_j[p];

    float dx, dy, dz, r, fr;
    int i0, i1;
    pair_geom(pos, i, j, inv_dr, rclip, dx, dy, dz, r, i0, i1, fr, n_r);

    int ti = types[i];
    int tj = types[j];

    float dens_j = interp_row(dens_tab + (size_t)tj * n_r, i0, i1, fr);
    float dens_i = interp_row(dens_tab + (size_t)ti * n_r, i0, i1, fr);

    atomic_add_f32(&rho[i], dens_j);
    atomic_add_f32(&rho[j], dens_i);
}

__global__ void eam_rho_reduce_kernel(const float* __restrict__ rho_reps,
                                      float* __restrict__ rho_final,
                                      int R, int N)
{
    int n = blockIdx.x * blockDim.x + threadIdx.x;
    if (n >= N) return;
    float s = 0.0f;
    for (int k = 0; k < R; ++k)
        s += rho_reps[(size_t)k * N + n];
    rho_final[n] = s;
}

__global__ void eam_force_kernel(
    const int* __restrict__ edge_i, const int* __restrict__ edge_j,
    const int* __restrict__ types, const float* __restrict__ pos,
    const float* __restrict__ dens_deriv_tab,
    const float* __restrict__ pair_deriv_tab,
    const float* __restrict__ rho,
    const float* __restrict__ embed_tab,
    const float* __restrict__ rho_min_t, const float* __restrict__ inv_drho_t,
    int n_r, int n_rho, int E, float inv_dr, float rclip, float one_m_eps,
    float* __restrict__ force_reps, int R, int N, int P)
{
    int p = blockIdx.x * blockDim.x + threadIdx.x;
    if (p >= P) return;

    float* forces = force_reps + (size_t)(blockIdx.x % R) * (3 * (size_t)N);

    int i = edge_i[p];
    int j = edge_j[p];

    float dx, dy, dz, r, fr;
    int i0, i1;
    pair_geom(pos, i, j, inv_dr, rclip, dx, dy, dz, r, i0, i1, fr, n_r);

    int ti = types[i];
    int tj = types[j];

    float ddens_j = interp_row(dens_deriv_tab + (size_t)tj * n_r, i0, i1, fr);
    float ddens_i = interp_row(dens_deriv_tab + (size_t)ti * n_r, i0, i1, fr);
    float dphi    = interp_row(pair_deriv_tab + ((size_t)ti * E + tj) * n_r, i0, i1, fr);

    float dFi = embed_dF(rho[i], ti, embed_tab, rho_min_t, inv_drho_t, n_rho, one_m_eps);
    float dFj = embed_dF(rho[j], tj, embed_tab, rho_min_t, inv_drho_t, n_rho, one_m_eps);

    float coeff = dFi * ddens_j + dFj * ddens_i + dphi;

    float fx = coeff * (dx / r);
    float fy = coeff * (dy / r);
    float fz = coeff * (dz / r);

    atomic_add_f32(&forces[3 * i + 0], -fx);
    atomic_add_f32(&forces[3 * i + 1], -fy);
    atomic_add_f32(&forces[3 * i + 2], -fz);
    atomic_add_f32(&forces[3 * j + 0],  fx);
    atomic_add_f32(&forces[3 * j + 1],  fy);
    atomic_add_f32(&forces[3 * j + 2],  fz);
}

__global__ void eam_force_reduce_kernel(const float* __restrict__ force_reps,
                                        float* __restrict__ forces,
                                        int R, int N3)
{
    int n = blockIdx.x * blockDim.x + threadIdx.x;
    if (n >= N3) return;
    float s = 0.0f;
    for (int k = 0; k < R; ++k)
        s += force_reps[(size_t)k * N3 + n];
    forces[n] = s;
}

extern "C" void kernel_launch(void* const* d_in, const int* in_sizes, int n_in,
                              void* d_out, int out_size, void* d_ws, size_t ws_size,
                              hipStream_t stream) {
    const float* positions        = (const float*)d_in[0];
    const float* density_table    = (const float*)d_in[1];
    const float* density_deriv    = (const float*)d_in[2];
    const float* pair_deriv       = (const float*)d_in[3];
    const float* embed_deriv      = (const float*)d_in[4];
    const float* embed_rho_min    = (const float*)d_in[5];
    const float* embed_inv_drho   = (const float*)d_in[6];
    const int*   atom_types       = (const int*)d_in[7];
    const int*   edge_i           = (const int*)d_in[8];
    const int*   edge_j           = (const int*)d_in[9];

    const int E     = in_sizes[5];
    const int N     = in_sizes[7];
    const int P     = in_sizes[8];
    const int n_r   = in_sizes[1] / E;
    const int n_rho = in_sizes[4] / E;

    const double R_MAX_d = 6.0;
    const double EPS_d   = 1e-7;
    const float inv_dr    = (float)((double)(n_r - 1) / R_MAX_d);
    const float rclip     = (float)(R_MAX_d * (1.0 - EPS_d));
    const float one_m_eps = (float)(1.0 - EPS_d);

    // choose replica count R (power of two, <=16) fitting ws: (1 + 4R)*N floats
    int R = 16;
    while (R > 1 && (size_t)(1 + 4 * (size_t)R) * N * sizeof(float) > ws_size) R >>= 1;
    if ((size_t)(1 + 4 * (size_t)R) * N * sizeof(float) > ws_size) R = 0;

    int pair_blocks = (P + EAM_BLOCK - 1) / EAM_BLOCK;

    if (R == 0) {
        // fallback: round-4 path (rho in ws, direct atomics into d_out)
        float* rho    = (float*)d_ws;
        float* forces = (float*)d_out;
        int zero_blocks = (3 * N + EAM_BLOCK - 1) / EAM_BLOCK;
        eam_zero_kernel<<<zero_blocks, EAM_BLOCK, 0, stream>>>(rho, forces, N);
        eam_density_kernel<<<pair_blocks, EAM_BLOCK, 0, stream>>>(
            edge_i, edge_j, atom_types, positions,
            density_table, n_r, inv_dr, rclip, rho, 1, N, P);
        eam_rho_reduce_kernel<<<(N + EAM_BLOCK - 1) / EAM_BLOCK, EAM_BLOCK, 0, stream>>>(
            rho, rho, 1, N);  // no-op copy keeps structure; rho already final
        eam_force_kernel<<<pair_blocks, EAM_BLOCK, 0, stream>>>(
            edge_i, edge_j, atom_types, positions,
            density_deriv, pair_deriv, rho,
            embed_deriv, embed_rho_min, embed_inv_drho,
            n_r, n_rho, E, inv_dr, rclip, one_m_eps, forces, 1, N, P);
        return;
    }

    float* rho_final  = (float*)d_ws;                       // N
    float* rho_reps   = rho_final + N;                      // R*N
    float* force_reps = rho_reps + (size_t)R * N;           // R*3N
    float* forces     = (float*)d_out;                      // 3N

    long long rep_floats = (long long)R * N + (long long)R * 3 * N;  // zero reps only
    long long n4 = rep_floats / 4;
    int zero_blocks = (int)((n4 + EAM_BLOCK - 1) / EAM_BLOCK);
    if (zero_blocks > 4096) zero_blocks = 4096;

    eam_zero4_kernel<<<zero_blocks, EAM_BLOCK, 0, stream>>>((float4*)rho_reps, n4);

    eam_density_kernel<<<pair_blocks, EAM_BLOCK, 0, stream>>>(
        edge_i, edge_j, atom_types, positions,
        density_table, n_r, inv_dr, rclip, rho_reps, R, N, P);

    eam_rho_reduce_kernel<<<(N + EAM_BLOCK - 1) / EAM_BLOCK, EAM_BLOCK, 0, stream>>>(
        rho_reps, rho_final, R, N);

    eam_force_kernel<<<pair_blocks, EAM_BLOCK, 0, stream>>>(
        edge_i, edge_j, atom_types, positions,
        density_deriv, pair_deriv, rho_final,
        embed_deriv, embed_rho_min, embed_inv_drho,
        n_r, n_rho, E, inv_dr, rclip, one_m_eps, force_reps, R, N, P);

    eam_force_reduce_kernel<<<(3 * N + EAM_BLOCK - 1) / EAM_BLOCK, EAM_BLOCK, 0, stream>>>(
        force_reps, forces, R, 3 * N);
}

// Round 6
// 2511.454 us; speedup vs baseline: 1.0063x; 1.0063x over previous
//
#include <hip/hip_runtime.h>

// EAM force, atomic-free scatter via bucket binning.
//
// Model (r3-r5 evidence): device-scope fp32 atomics cost ~49ns each chip-wide
// (20.5G trans/s) independent of address distribution (replication null,
// native-vs-CAS null; time == trans/20.5G exactly for both pair kernels).
// Fix: issue ZERO global fp atomics. Pairs bin (atom, value) records by
// 1024-atom bucket (per-block LDS counting sort, one cursor atomic per
// block-bucket); per-bucket blocks accumulate records in LDS and store slabs.
//
// Pipeline: zero_meta -> count -> scan -> bin_density -> acc_density(rho)
//           -> bin_force -> acc_force(forces)
// ws: counts/base/curD/curF [256 ints each] | rho[N] | recA_D,recV_D[2P]
//     | recA_F,recX,recY,recZ[2P].  Fallback to direct-atomic path if small.

#define BLK 256
#define SHIFT 10
#define BSZ 1024          // atoms per bucket
#define NBPAD 256         // padded bucket count (NB = ceil(N/BSZ) <= 256)
#define PPB_D 2048        // pairs per block in density binning (8/thread)
#define PPB_F 1024        // pairs per block in force binning   (4/thread)

__device__ __forceinline__ float interp_row(const float* __restrict__ row,
                                            int i0, int i1, float fr) {
    float a = row[i0];
    float b = row[i1];
    return a + fr * (b - a);
}

__device__ __forceinline__ float embed_dF(float rho, int t,
                                          const float* __restrict__ embed_tab,
                                          const float* __restrict__ rho_min_t,
                                          const float* __restrict__ inv_drho_t,
                                          int n_rho, float one_m_eps) {
    float rmin = rho_min_t[t];
    float invd = inv_drho_t[t];
    float hi = rmin + (float)(n_rho - 1) / invd * one_m_eps;
    float rc = fminf(fmaxf(rho, rmin), hi);
    float g  = (rc - rmin) * invd;
    int  g0  = (int)g;
    g0 = g0 < 0 ? 0 : (g0 > n_rho - 2 ? n_rho - 2 : g0);
    float gfr = g - (float)g0;
    const float* row = embed_tab + (size_t)t * n_rho;
    float e0 = row[g0];
    float e1 = row[g0 + 1];
    return e0 + gfr * (e1 - e0);
}

__device__ __forceinline__ void pair_geom(
    const float* __restrict__ pos, int i, int j,
    float inv_dr, float rclip,
    float& dx, float& dy, float& dz, float& r,
    int& i0, int& i1, float& fr, int n_r)
{
#pragma clang fp contract(off)
    float xi = pos[3 * i + 0], yi = pos[3 * i + 1], zi = pos[3 * i + 2];
    float xj = pos[3 * j + 0], yj = pos[3 * j + 1], zj = pos[3 * j + 2];
    dx = xj - xi; dy = yj - yi; dz = zj - zi;
    float s = dx * dx;
    s = s + dy * dy;
    s = s + dz * dz;
    s = s + 1e-12f;
    r = sqrtf(s);

    float rc = fminf(fmaxf(r, 0.0f), rclip);
    float f  = rc * inv_dr;
    i0 = (int)f;
    fr = f - (float)i0;
    i1 = min(i0 + 1, n_r - 1);
}

// ---------------- binning pipeline kernels ----------------

__global__ void eam_zero_meta(int* __restrict__ counts) {
    counts[threadIdx.x] = 0;
}

__global__ void eam_count_kernel(const int* __restrict__ ei,
                                 const int* __restrict__ ej,
                                 int* __restrict__ counts, int P)
{
    __shared__ int cnt[NBPAD];
    for (int k = threadIdx.x; k < NBPAD; k += BLK) cnt[k] = 0;
    __syncthreads();
    for (int p = blockIdx.x * BLK + threadIdx.x; p < P; p += gridDim.x * BLK) {
        atomicAdd(&cnt[((unsigned)ei[p]) >> SHIFT], 1);
        atomicAdd(&cnt[((unsigned)ej[p]) >> SHIFT], 1);
    }
    __syncthreads();
    for (int k = threadIdx.x; k < NBPAD; k += BLK)
        if (cnt[k]) atomicAdd(&counts[k], cnt[k]);
}

__global__ void eam_scan_kernel(const int* __restrict__ counts,
                                int* __restrict__ base,
                                int* __restrict__ curD,
                                int* __restrict__ curF)
{
    __shared__ int s[NBPAD];
    int t = threadIdx.x;
    int c = counts[t];
    s[t] = c;
    __syncthreads();
    for (int d = 1; d < NBPAD; d <<= 1) {
        int v = (t >= d) ? s[t - d] : 0;
        __syncthreads();
        s[t] += v;
        __syncthreads();
    }
    int b = s[t] - c;   // exclusive prefix
    base[t] = b; curD[t] = b; curF[t] = b;
}

__global__ __launch_bounds__(BLK) void eam_bin_density(
    const int* __restrict__ ei, const int* __restrict__ ej,
    const int* __restrict__ types, const float* __restrict__ pos,
    const float* __restrict__ dens_tab, int n_r, float inv_dr, float rclip,
    int* __restrict__ curD, unsigned* __restrict__ recA,
    float* __restrict__ recV, int P)
{
    __shared__ int cnt[NBPAD], off[NBPAD], cur[NBPAD], gb[NBPAD], sc[NBPAD];
    __shared__ unsigned sA[2 * PPB_D];
    __shared__ float    sV[2 * PPB_D];
    const int tid  = threadIdx.x;
    const int tile = blockIdx.x * PPB_D;

    for (int k = tid; k < NBPAD; k += BLK) cnt[k] = 0;
    __syncthreads();

    unsigned ra[16]; float rv[16]; bool valid[8];
#pragma unroll
    for (int k = 0; k < 8; ++k) {
        int p = tile + tid + k * BLK;
        valid[k] = (p < P);
        unsigned i = 0, j = 0; float d_j = 0.f, d_i = 0.f;
        if (valid[k]) {
            i = (unsigned)ei[p]; j = (unsigned)ej[p];
            float dx, dy, dz, r, fr; int i0, i1;
            pair_geom(pos, (int)i, (int)j, inv_dr, rclip, dx, dy, dz, r, i0, i1, fr, n_r);
            int ti = types[i], tj = types[j];
            d_j = interp_row(dens_tab + (size_t)tj * n_r, i0, i1, fr);
            d_i = interp_row(dens_tab + (size_t)ti * n_r, i0, i1, fr);
            atomicAdd(&cnt[i >> SHIFT], 1);
            atomicAdd(&cnt[j >> SHIFT], 1);
        }
        ra[2 * k] = i;     rv[2 * k] = d_j;
        ra[2 * k + 1] = j; rv[2 * k + 1] = d_i;
    }
    __syncthreads();

    int c = cnt[tid];
    sc[tid] = c;
    __syncthreads();
    for (int d = 1; d < NBPAD; d <<= 1) {
        int v = (tid >= d) ? sc[tid - d] : 0;
        __syncthreads();
        sc[tid] += v;
        __syncthreads();
    }
    int o = sc[tid] - c;
    off[tid] = o; cur[tid] = o;
    if (c > 0) gb[tid] = atomicAdd(&curD[tid], c);
    __syncthreads();

#pragma unroll
    for (int k = 0; k < 8; ++k) if (valid[k]) {
#pragma unroll
        for (int s2 = 0; s2 < 2; ++s2) {
            unsigned a = ra[2 * k + s2];
            int b = a >> SHIFT;
            int sl = atomicAdd(&cur[b], 1);
            sA[sl] = a; sV[sl] = rv[2 * k + s2];
        }
    }
    __syncthreads();

    int total = off[NBPAD - 1] + cnt[NBPAD - 1];
    for (int s2 = tid; s2 < total; s2 += BLK) {
        unsigned a = sA[s2];
        int b = a >> SHIFT;
        int dst = gb[b] + (s2 - off[b]);
        recA[dst] = a; recV[dst] = sV[s2];
    }
}

__global__ __launch_bounds__(BLK) void eam_acc_density(
    const unsigned* __restrict__ recA, const float* __restrict__ recV,
    const int* __restrict__ base, const int* __restrict__ counts,
    float* __restrict__ rho, int N)
{
    __shared__ float acc[BSZ];
    int b = blockIdx.x;
    for (int k = threadIdx.x; k < BSZ; k += BLK) acc[k] = 0.f;
    __syncthreads();
    int s = base[b], e = s + counts[b];
    for (int q = s + threadIdx.x; q < e; q += BLK)
        atomicAdd(&acc[recA[q] & (BSZ - 1)], recV[q]);
    __syncthreads();
    int abase = b << SHIFT;
    for (int k = threadIdx.x; k < BSZ; k += BLK) {
        int a = abase + k;
        if (a < N) rho[a] = acc[k];
    }
}

__global__ __launch_bounds__(BLK) void eam_bin_force(
    const int* __restrict__ ei, const int* __restrict__ ej,
    const int* __restrict__ types, const float* __restrict__ pos,
    const float* __restrict__ dens_deriv_tab,
    const float* __restrict__ pair_deriv_tab,
    const float* __restrict__ rho,
    const float* __restrict__ embed_tab,
    const float* __restrict__ rho_min_t, const float* __restrict__ inv_drho_t,
    int n_r, int n_rho, int E, float inv_dr, float rclip, float one_m_eps,
    int* __restrict__ curF, unsigned* __restrict__ recA,
    float* __restrict__ recX, float* __restrict__ recY, float* __restrict__ recZ,
    int P)
{
    __shared__ int cnt[NBPAD], off[NBPAD], cur[NBPAD], gb[NBPAD], sc[NBPAD];
    __shared__ unsigned sA[2 * PPB_F];
    __shared__ float sX[2 * PPB_F], sY[2 * PPB_F], sZ[2 * PPB_F];
    const int tid  = threadIdx.x;
    const int tile = blockIdx.x * PPB_F;

    for (int k = tid; k < NBPAD; k += BLK) cnt[k] = 0;
    __syncthreads();

    unsigned ia[4], ja[4];
    float fx[4], fy[4], fz[4];
    bool valid[4];
#pragma unroll
    for (int k = 0; k < 4; ++k) {
        int p = tile + tid + k * BLK;
        valid[k] = (p < P);
        unsigned i = 0, j = 0; float vx = 0.f, vy = 0.f, vz = 0.f;
        if (valid[k]) {
            i = (unsigned)ei[p]; j = (unsigned)ej[p];
            float dx, dy, dz, r, fr; int i0, i1;
            pair_geom(pos, (int)i, (int)j, inv_dr, rclip, dx, dy, dz, r, i0, i1, fr, n_r);
            int ti = types[i], tj = types[j];
            float ddens_j = interp_row(dens_deriv_tab + (size_t)tj * n_r, i0, i1, fr);
            float ddens_i = interp_row(dens_deriv_tab + (size_t)ti * n_r, i0, i1, fr);
            float dphi    = interp_row(pair_deriv_tab + ((size_t)ti * E + tj) * n_r, i0, i1, fr);
            float dFi = embed_dF(rho[i], ti, embed_tab, rho_min_t, inv_drho_t, n_rho, one_m_eps);
            float dFj = embed_dF(rho[j], tj, embed_tab, rho_min_t, inv_drho_t, n_rho, one_m_eps);
            float coeff = dFi * ddens_j + dFj * ddens_i + dphi;
            vx = coeff * (dx / r);
            vy = coeff * (dy / r);
            vz = coeff * (dz / r);
            atomicAdd(&cnt[i >> SHIFT], 1);
            atomicAdd(&cnt[j >> SHIFT], 1);
        }
        ia[k] = i; ja[k] = j; fx[k] = vx; fy[k] = vy; fz[k] = vz;
    }
    __syncthreads();

    int c = cnt[tid];
    sc[tid] = c;
    __syncthreads();
    for (int d = 1; d < NBPAD; d <<= 1) {
        int v = (tid >= d) ? sc[tid - d] : 0;
        __syncthreads();
        sc[tid] += v;
        __syncthreads();
    }
    int o = sc[tid] - c;
    off[tid] = o; cur[tid] = o;
    if (c > 0) gb[tid] = atomicAdd(&curF[tid], c);
    __syncthreads();

#pragma unroll
    for (int k = 0; k < 4; ++k) if (valid[k]) {
        {   // endpoint i gets -f
            unsigned a = ia[k];
            int b = a >> SHIFT;
            int sl = atomicAdd(&cur[b], 1);
            sA[sl] = a; sX[sl] = -fx[k]; sY[sl] = -fy[k]; sZ[sl] = -fz[k];
        }
        {   // endpoint j gets +f
            unsigned a = ja[k];
            int b = a >> SHIFT;
            int sl = atomicAdd(&cur[b], 1);
            sA[sl] = a; sX[sl] = fx[k]; sY[sl] = fy[k]; sZ[sl] = fz[k];
        }
    }
    __syncthreads();

    int total = off[NBPAD - 1] + cnt[NBPAD - 1];
    for (int s2 = tid; s2 < total; s2 += BLK) {
        unsigned a = sA[s2];
        int b = a >> SHIFT;
        int dst = gb[b] + (s2 - off[b]);
        recA[dst] = a;
        recX[dst] = sX[s2];
        recY[dst] = sY[s2];
        recZ[dst] = sZ[s2];
    }
}

__global__ __launch_bounds__(BLK) void eam_acc_force(
    const unsigned* __restrict__ recA,
    const float* __restrict__ recX, const float* __restrict__ recY,
    const float* __restrict__ recZ,
    const int* __restrict__ base, const int* __restrict__ counts,
    float* __restrict__ forces, int N)
{
    __shared__ float acc[3 * BSZ];
    int b = blockIdx.x;
    for (int k = threadIdx.x; k < 3 * BSZ; k += BLK) acc[k] = 0.f;
    __syncthreads();
    int s = base[b], e = s + counts[b];
    for (int q = s + threadIdx.x; q < e; q += BLK) {
        int loc = (int)(recA[q] & (BSZ - 1)) * 3;
        atomicAdd(&acc[loc + 0], recX[q]);
        atomicAdd(&acc[loc + 1], recY[q]);
        atomicAdd(&acc[loc + 2], recZ[q]);
    }
    __syncthreads();
    int abase = b << SHIFT;
    int lim = 3 * (N - abase);
    if (lim > 3 * BSZ) lim = 3 * BSZ;
    for (int k = threadIdx.x; k < lim; k += BLK)
        forces[3 * abase + k] = acc[k];
}

// ---------------- fallback: direct-atomic path (round-4) ----------------

__global__ void eam_zero_kernel(float* __restrict__ rho,
                                float* __restrict__ forces, int N) {
    int idx = blockIdx.x * blockDim.x + threadIdx.x;
    if (idx < N) rho[idx] = 0.0f;
    if (idx < 3 * N) forces[idx] = 0.0f;
}

__global__ void eam_density_direct(
    const int* __restrict__ ei, const int* __restrict__ ej,
    const int* __restrict__ types, const float* __restrict__ pos,
    const float* __restrict__ dens_tab, int n_r, float inv_dr, float rclip,
    float* __restrict__ rho, int P)
{
    int p = blockIdx.x * blockDim.x + threadIdx.x;
    if (p >= P) return;
    int i = ei[p], j = ej[p];
    float dx, dy, dz, r, fr; int i0, i1;
    pair_geom(pos, i, j, inv_dr, rclip, dx, dy, dz, r, i0, i1, fr, n_r);
    int ti = types[i], tj = types[j];
    unsafeAtomicAdd(&rho[i], interp_row(dens_tab + (size_t)tj * n_r, i0, i1, fr));
    unsafeAtomicAdd(&rho[j], interp_row(dens_tab + (size_t)ti * n_r, i0, i1, fr));
}

__global__ void eam_force_direct(
    const int* __restrict__ ei, const int* __restrict__ ej,
    const int* __restrict__ types, const float* __restrict__ pos,
    const float* __restrict__ dens_deriv_tab,
    const float* __restrict__ pair_deriv_tab,
    const float* __restrict__ rho,
    const float* __restrict__ embed_tab,
    const float* __restrict__ rho_min_t, const float* __restrict__ inv_drho_t,
    int n_r, int n_rho, int E, float inv_dr, float rclip, float one_m_eps,
    float* __restrict__ forces, int P)
{
    int p = blockIdx.x * blockDim.x + threadIdx.x;
    if (p >= P) return;
    int i = ei[p], j = ej[p];
    float dx, dy, dz, r, fr; int i0, i1;
    pair_geom(pos, i, j, inv_dr, rclip, dx, dy, dz, r, i0, i1, fr, n_r);
    int ti = types[i], tj = types[j];
    float ddens_j = interp_row(dens_deriv_tab + (size_t)tj * n_r, i0, i1, fr);
    float ddens_i = interp_row(dens_deriv_tab + (size_t)ti * n_r, i0, i1, fr);
    float dphi    = interp_row(pair_deriv_tab + ((size_t)ti * E + tj) * n_r, i0, i1, fr);
    float dFi = embed_dF(rho[i], ti, embed_tab, rho_min_t, inv_drho_t, n_rho, one_m_eps);
    float dFj = embed_dF(rho[j], tj, embed_tab, rho_min_t, inv_drho_t, n_rho, one_m_eps);
    float coeff = dFi * ddens_j + dFj * ddens_i + dphi;
    float fxv = coeff * (dx / r), fyv = coeff * (dy / r), fzv = coeff * (dz / r);
    unsafeAtomicAdd(&forces[3 * i + 0], -fxv);
    unsafeAtomicAdd(&forces[3 * i + 1], -fyv);
    unsafeAtomicAdd(&forces[3 * i + 2], -fzv);
    unsafeAtomicAdd(&forces[3 * j + 0],  fxv);
    unsafeAtomicAdd(&forces[3 * j + 1],  fyv);
    unsafeAtomicAdd(&forces[3 * j + 2],  fzv);
}

// ---------------- launcher ----------------

extern "C" void kernel_launch(void* const* d_in, const int* in_sizes, int n_in,
                              void* d_out, int out_size, void* d_ws, size_t ws_size,
                              hipStream_t stream) {
    const float* positions      = (const float*)d_in[0];
    const float* density_table  = (const float*)d_in[1];
    const float* density_deriv  = (const float*)d_in[2];
    const float* pair_deriv     = (const float*)d_in[3];
    const float* embed_deriv    = (const float*)d_in[4];
    const float* embed_rho_min  = (const float*)d_in[5];
    const float* embed_inv_drho = (const float*)d_in[6];
    const int*   atom_types     = (const int*)d_in[7];
    const int*   edge_i         = (const int*)d_in[8];
    const int*   edge_j         = (const int*)d_in[9];

    const int E     = in_sizes[5];
    const int N     = in_sizes[7];
    const int P     = in_sizes[8];
    const int n_r   = in_sizes[1] / E;
    const int n_rho = in_sizes[4] / E;

    const double R_MAX_d = 6.0;
    const double EPS_d   = 1e-7;
    const float inv_dr    = (float)((double)(n_r - 1) / R_MAX_d);
    const float rclip     = (float)(R_MAX_d * (1.0 - EPS_d));
    const float one_m_eps = (float)(1.0 - EPS_d);

    float* forces = (float*)d_out;

    // workspace layout
    const size_t PR = 2 * (size_t)P;   // directed records
    char* wp = (char*)d_ws;
    int* counts = (int*)wp;            wp += NBPAD * sizeof(int);
    int* base   = (int*)wp;            wp += NBPAD * sizeof(int);
    int* curD   = (int*)wp;            wp += NBPAD * sizeof(int);
    int* curF   = (int*)wp;            wp += NBPAD * sizeof(int);
    float*    rho    = (float*)wp;     wp += (size_t)N * sizeof(float);
    unsigned* recA_D = (unsigned*)wp;  wp += PR * sizeof(unsigned);
    float*    recV_D = (float*)wp;     wp += PR * sizeof(float);
    unsigned* recA_F = (unsigned*)wp;  wp += PR * sizeof(unsigned);
    float*    recX   = (float*)wp;     wp += PR * sizeof(float);
    float*    recY   = (float*)wp;     wp += PR * sizeof(float);
    float*    recZ   = (float*)wp;     wp += PR * sizeof(float);
    size_t need = (size_t)(wp - (char*)d_ws);

    const int NB = (N + BSZ - 1) >> SHIFT;

    if (need > ws_size || NB > NBPAD) {
        // fallback: direct-atomic path (round-4 behavior)
        float* rho_f = (float*)d_ws;
        int zero_blocks = (3 * N + BLK - 1) / BLK;
        int pair_blocks = (P + BLK - 1) / BLK;
        eam_zero_kernel<<<zero_blocks, BLK, 0, stream>>>(rho_f, forces, N);
        eam_density_direct<<<pair_blocks, BLK, 0, stream>>>(
            edge_i, edge_j, atom_types, positions,
            density_table, n_r, inv_dr, rclip, rho_f, P);
        eam_force_direct<<<pair_blocks, BLK, 0, stream>>>(
            edge_i, edge_j, atom_types, positions,
            density_deriv, pair_deriv, rho_f,
            embed_deriv, embed_rho_min, embed_inv_drho,
            n_r, n_rho, E, inv_dr, rclip, one_m_eps, forces, P);
        return;
    }

    eam_zero_meta<<<1, NBPAD, 0, stream>>>(counts);
    eam_count_kernel<<<1024, BLK, 0, stream>>>(edge_i, edge_j, counts, P);
    eam_scan_kernel<<<1, NBPAD, 0, stream>>>(counts, base, curD, curF);

    int binD_blocks = (P + PPB_D - 1) / PPB_D;
    eam_bin_density<<<binD_blocks, BLK, 0, stream>>>(
        edge_i, edge_j, atom_types, positions,
        density_table, n_r, inv_dr, rclip,
        curD, recA_D, recV_D, P);

    eam_acc_density<<<NB, BLK, 0, stream>>>(recA_D, recV_D, base, counts, rho, N);

    int binF_blocks = (P + PPB_F - 1) / PPB_F;
    eam_bin_force<<<binF_blocks, BLK, 0, stream>>>(
        edge_i, edge_j, atom_types, positions,
        density_deriv, pair_deriv, rho,
        embed_deriv, embed_rho_min, embed_inv_drho,
        n_r, n_rho, E, inv_dr, rclip, one_m_eps,
        curF, recA_F, recX, recY, recZ, P);

    eam_acc_force<<<NB, BLK, 0, stream>>>(recA_F, recX, recY, recZ,
                                          base, counts, forces, N);
}

// Round 7
// 2509.573 us; speedup vs baseline: 1.0071x; 1.0007x over previous
//
#include <hip/hip_runtime.h>
#include <stdint.h>

// EAM force with per-XCD replicated accumulators + XCD-local (L2) atomics.
//
// Evidence r3-r6: agent-scope fp32 atomics = 32B fabric transaction each,
// ~20.4G/s chip-wide, independent of address distribution -> executed past
// the (non-cross-coherent) per-XCD L2 at the coherence point. Fix: replicate
// accumulators 8x, index by hardware XCC_ID, and issue raw
// global_atomic_add_f32 with NO sc bits -> executes in the XCD-local L2 at
// full rate; dirty lines written back once at kernel-end (same mechanism that
// makes ordinary cross-XCD stores coherent between dependent kernels).
//
// Tier A (ws >= ~26MB): dF[N] | rho_reps[8N] | force_reps[24N]
//   zero4 -> density_rep -> rho_reduce+embed(dF) -> force_rep -> force_reduce
// Tier B (ws >= ~7MB):  dF[N] | rho_reps[8N]; forces via direct agent atomics
// Tier C: round-4 direct path.

#define BLK 256
#define NXCC 8

__device__ __forceinline__ int xcc_id() {
    unsigned v;
    asm("s_getreg_b32 %0, hwreg(HW_REG_XCC_ID)" : "=s"(v));
    return (int)(v & (NXCC - 1));
}

// fp32 atomic executed at the XCD-local L2 (no sc0/sc1 -> not forwarded to
// the device coherence point). Only safe because each XCD owns its replica.
__device__ __forceinline__ void l2_atomic_add(float* p, float v) {
    asm volatile("global_atomic_add_f32 %0, %1, off"
                 :: "v"(p), "v"(v) : "memory");
}

__device__ __forceinline__ float interp_row(const float* __restrict__ row,
                                            int i0, int i1, float fr) {
    float a = row[i0];
    float b = row[i1];
    return a + fr * (b - a);
}

__device__ __forceinline__ float embed_dF(float rho, int t,
                                          const float* __restrict__ embed_tab,
                                          const float* __restrict__ rho_min_t,
                                          const float* __restrict__ inv_drho_t,
                                          int n_rho, float one_m_eps) {
    float rmin = rho_min_t[t];
    float invd = inv_drho_t[t];
    float hi = rmin + (float)(n_rho - 1) / invd * one_m_eps;
    float rc = fminf(fmaxf(rho, rmin), hi);
    float g  = (rc - rmin) * invd;
    int  g0  = (int)g;
    g0 = g0 < 0 ? 0 : (g0 > n_rho - 2 ? n_rho - 2 : g0);
    float gfr = g - (float)g0;
    const float* row = embed_tab + (size_t)t * n_rho;
    float e0 = row[g0];
    float e1 = row[g0 + 1];
    return e0 + gfr * (e1 - e0);
}

__device__ __forceinline__ void pair_geom(
    const float* __restrict__ pos, int i, int j,
    float inv_dr, float rclip,
    float& dx, float& dy, float& dz, float& r,
    int& i0, int& i1, float& fr, int n_r)
{
#pragma clang fp contract(off)
    float xi = pos[3 * i + 0], yi = pos[3 * i + 1], zi = pos[3 * i + 2];
    float xj = pos[3 * j + 0], yj = pos[3 * j + 1], zj = pos[3 * j + 2];
    dx = xj - xi; dy = yj - yi; dz = zj - zi;
    float s = dx * dx;
    s = s + dy * dy;
    s = s + dz * dz;
    s = s + 1e-12f;
    r = sqrtf(s);

    float rc = fminf(fmaxf(r, 0.0f), rclip);
    float f  = rc * inv_dr;
    i0 = (int)f;
    fr = f - (float)i0;
    i1 = min(i0 + 1, n_r - 1);
}

__global__ void eam_zero4_kernel(float4* __restrict__ p, long long n4) {
    long long idx = (long long)blockIdx.x * blockDim.x + threadIdx.x;
    long long stride = (long long)gridDim.x * blockDim.x;
    for (; idx < n4; idx += stride)
        p[idx] = make_float4(0.f, 0.f, 0.f, 0.f);
}

__global__ void eam_zero_kernel(float* __restrict__ a, int n) {
    int idx = blockIdx.x * blockDim.x + threadIdx.x;
    if (idx < n) a[idx] = 0.0f;
}

// ---- Tier A/B: density with per-XCD replicas, L2-local atomics ----

__global__ void eam_density_rep(
    const int* __restrict__ ei, const int* __restrict__ ej,
    const int* __restrict__ types, const float* __restrict__ pos,
    const float* __restrict__ dens_tab, int n_r, float inv_dr, float rclip,
    float* __restrict__ rho_reps, int N, int P)
{
    int p = blockIdx.x * blockDim.x + threadIdx.x;
    if (p >= P) return;

    float* rho = rho_reps + (size_t)xcc_id() * N;

    int i = ei[p], j = ej[p];
    float dx, dy, dz, r, fr; int i0, i1;
    pair_geom(pos, i, j, inv_dr, rclip, dx, dy, dz, r, i0, i1, fr, n_r);
    int ti = types[i], tj = types[j];

    l2_atomic_add(&rho[i], interp_row(dens_tab + (size_t)tj * n_r, i0, i1, fr));
    l2_atomic_add(&rho[j], interp_row(dens_tab + (size_t)ti * n_r, i0, i1, fr));
    asm volatile("s_waitcnt vmcnt(0)");
}

// rho = sum of 8 replicas, then dF = F'(rho) once per atom (as the reference)
__global__ void eam_rho_embed(
    const float* __restrict__ rho_reps, const int* __restrict__ types,
    const float* __restrict__ embed_tab,
    const float* __restrict__ rho_min_t, const float* __restrict__ inv_drho_t,
    int n_rho, float one_m_eps, float* __restrict__ dF, int N)
{
    int n = blockIdx.x * blockDim.x + threadIdx.x;
    if (n >= N) return;
    float s = 0.0f;
#pragma unroll
    for (int k = 0; k < NXCC; ++k)
        s += rho_reps[(size_t)k * N + n];
    dF[n] = embed_dF(s, types[n], embed_tab, rho_min_t, inv_drho_t,
                     n_rho, one_m_eps);
}

// ---- Tier A: force with per-XCD replicas ----

__global__ void eam_force_rep(
    const int* __restrict__ ei, const int* __restrict__ ej,
    const int* __restrict__ types, const float* __restrict__ pos,
    const float* __restrict__ dens_deriv_tab,
    const float* __restrict__ pair_deriv_tab,
    const float* __restrict__ dF,
    int n_r, int E, float inv_dr, float rclip,
    float* __restrict__ force_reps, int N, int P)
{
    int p = blockIdx.x * blockDim.x + threadIdx.x;
    if (p >= P) return;

    float* F = force_reps + (size_t)xcc_id() * 3 * (size_t)N;

    int i = ei[p], j = ej[p];
    float dx, dy, dz, r, fr; int i0, i1;
    pair_geom(pos, i, j, inv_dr, rclip, dx, dy, dz, r, i0, i1, fr, n_r);
    int ti = types[i], tj = types[j];

    float ddens_j = interp_row(dens_deriv_tab + (size_t)tj * n_r, i0, i1, fr);
    float ddens_i = interp_row(dens_deriv_tab + (size_t)ti * n_r, i0, i1, fr);
    float dphi    = interp_row(pair_deriv_tab + ((size_t)ti * E + tj) * n_r, i0, i1, fr);

    float coeff = dF[i] * ddens_j + dF[j] * ddens_i + dphi;

    float fx = coeff * (dx / r);
    float fy = coeff * (dy / r);
    float fz = coeff * (dz / r);

    l2_atomic_add(&F[3 * i + 0], -fx);
    l2_atomic_add(&F[3 * i + 1], -fy);
    l2_atomic_add(&F[3 * i + 2], -fz);
    l2_atomic_add(&F[3 * j + 0],  fx);
    l2_atomic_add(&F[3 * j + 1],  fy);
    l2_atomic_add(&F[3 * j + 2],  fz);
    asm volatile("s_waitcnt vmcnt(0)");
}

__global__ void eam_force_reduce(const float* __restrict__ force_reps,
                                 float* __restrict__ forces, int N3)
{
    int n = blockIdx.x * blockDim.x + threadIdx.x;
    if (n >= N3) return;
    float s = 0.0f;
#pragma unroll
    for (int k = 0; k < NXCC; ++k)
        s += force_reps[(size_t)k * N3 + n];
    forces[n] = s;
}

// ---- Tier B force / Tier C kernels (direct agent atomics) ----

__global__ void eam_force_direct_dF(
    const int* __restrict__ ei, const int* __restrict__ ej,
    const int* __restrict__ types, const float* __restrict__ pos,
    const float* __restrict__ dens_deriv_tab,
    const float* __restrict__ pair_deriv_tab,
    const float* __restrict__ dF,
    int n_r, int E, float inv_dr, float rclip,
    float* __restrict__ forces, int P)
{
    int p = blockIdx.x * blockDim.x + threadIdx.x;
    if (p >= P) return;
    int i = ei[p], j = ej[p];
    float dx, dy, dz, r, fr; int i0, i1;
    pair_geom(pos, i, j, inv_dr, rclip, dx, dy, dz, r, i0, i1, fr, n_r);
    int ti = types[i], tj = types[j];
    float ddens_j = interp_row(dens_deriv_tab + (size_t)tj * n_r, i0, i1, fr);
    float ddens_i = interp_row(dens_deriv_tab + (size_t)ti * n_r, i0, i1, fr);
    float dphi    = interp_row(pair_deriv_tab + ((size_t)ti * E + tj) * n_r, i0, i1, fr);
    float coeff = dF[i] * ddens_j + dF[j] * ddens_i + dphi;
    float fx = coeff * (dx / r), fy = coeff * (dy / r), fz = coeff * (dz / r);
    unsafeAtomicAdd(&forces[3 * i + 0], -fx);
    unsafeAtomicAdd(&forces[3 * i + 1], -fy);
    unsafeAtomicAdd(&forces[3 * i + 2], -fz);
    unsafeAtomicAdd(&forces[3 * j + 0],  fx);
    unsafeAtomicAdd(&forces[3 * j + 1],  fy);
    unsafeAtomicAdd(&forces[3 * j + 2],  fz);
}

__global__ void eam_density_direct(
    const int* __restrict__ ei, const int* __restrict__ ej,
    const int* __restrict__ types, const float* __restrict__ pos,
    const float* __restrict__ dens_tab, int n_r, float inv_dr, float rclip,
    float* __restrict__ rho, int P)
{
    int p = blockIdx.x * blockDim.x + threadIdx.x;
    if (p >= P) return;
    int i = ei[p], j = ej[p];
    float dx, dy, dz, r, fr; int i0, i1;
    pair_geom(pos, i, j, inv_dr, rclip, dx, dy, dz, r, i0, i1, fr, n_r);
    int ti = types[i], tj = types[j];
    unsafeAtomicAdd(&rho[i], interp_row(dens_tab + (size_t)tj * n_r, i0, i1, fr));
    unsafeAtomicAdd(&rho[j], interp_row(dens_tab + (size_t)ti * n_r, i0, i1, fr));
}

__global__ void eam_force_direct_embed(
    const int* __restrict__ ei, const int* __restrict__ ej,
    const int* __restrict__ types, const float* __restrict__ pos,
    const float* __restrict__ dens_deriv_tab,
    const float* __restrict__ pair_deriv_tab,
    const float* __restrict__ rho,
    const float* __restrict__ embed_tab,
    const float* __restrict__ rho_min_t, const float* __restrict__ inv_drho_t,
    int n_r, int n_rho, int E, float inv_dr, float rclip, float one_m_eps,
    float* __restrict__ forces, int P)
{
    int p = blockIdx.x * blockDim.x + threadIdx.x;
    if (p >= P) return;
    int i = ei[p], j = ej[p];
    float dx, dy, dz, r, fr; int i0, i1;
    pair_geom(pos, i, j, inv_dr, rclip, dx, dy, dz, r, i0, i1, fr, n_r);
    int ti = types[i], tj = types[j];
    float ddens_j = interp_row(dens_deriv_tab + (size_t)tj * n_r, i0, i1, fr);
    float ddens_i = interp_row(dens_deriv_tab + (size_t)ti * n_r, i0, i1, fr);
    float dphi    = interp_row(pair_deriv_tab + ((size_t)ti * E + tj) * n_r, i0, i1, fr);
    float dFi = embed_dF(rho[i], ti, embed_tab, rho_min_t, inv_drho_t, n_rho, one_m_eps);
    float dFj = embed_dF(rho[j], tj, embed_tab, rho_min_t, inv_drho_t, n_rho, one_m_eps);
    float coeff = dFi * ddens_j + dFj * ddens_i + dphi;
    float fx = coeff * (dx / r), fy = coeff * (dy / r), fz = coeff * (dz / r);
    unsafeAtomicAdd(&forces[3 * i + 0], -fx);
    unsafeAtomicAdd(&forces[3 * i + 1], -fy);
    unsafeAtomicAdd(&forces[3 * i + 2], -fz);
    unsafeAtomicAdd(&forces[3 * j + 0],  fx);
    unsafeAtomicAdd(&forces[3 * j + 1],  fy);
    unsafeAtomicAdd(&forces[3 * j + 2],  fz);
}

// ---- launcher ----

extern "C" void kernel_launch(void* const* d_in, const int* in_sizes, int n_in,
                              void* d_out, int out_size, void* d_ws, size_t ws_size,
                              hipStream_t stream) {
    const float* positions      = (const float*)d_in[0];
    const float* density_table  = (const float*)d_in[1];
    const float* density_deriv  = (const float*)d_in[2];
    const float* pair_deriv     = (const float*)d_in[3];
    const float* embed_deriv    = (const float*)d_in[4];
    const float* embed_rho_min  = (const float*)d_in[5];
    const float* embed_inv_drho = (const float*)d_in[6];
    const int*   atom_types     = (const int*)d_in[7];
    const int*   edge_i         = (const int*)d_in[8];
    const int*   edge_j         = (const int*)d_in[9];

    const int E     = in_sizes[5];
    const int N     = in_sizes[7];
    const int P     = in_sizes[8];
    const int n_r   = in_sizes[1] / E;
    const int n_rho = in_sizes[4] / E;

    const double R_MAX_d = 6.0;
    const double EPS_d   = 1e-7;
    const float inv_dr    = (float)((double)(n_r - 1) / R_MAX_d);
    const float rclip     = (float)(R_MAX_d * (1.0 - EPS_d));
    const float one_m_eps = (float)(1.0 - EPS_d);

    float* forces = (float*)d_out;

    const size_t Npad = ((size_t)N + 3) & ~(size_t)3;   // keep 16B alignment
    const size_t needA = (Npad + 32 * (size_t)N) * sizeof(float);
    const size_t needB = (Npad + 8 * (size_t)N) * sizeof(float);

    const int pair_blocks = (P + BLK - 1) / BLK;
    const int atom_blocks = (N + BLK - 1) / BLK;

    if (needA <= ws_size) {
        // Tier A: fully replicated
        float* dF         = (float*)d_ws;
        float* rho_reps   = dF + Npad;                       // 8N
        float* force_reps = rho_reps + 8 * (size_t)N;        // 24N

        long long n4 = (32LL * N) / 4;
        int zb = (int)((n4 + BLK - 1) / BLK);
        if (zb > 4096) zb = 4096;
        eam_zero4_kernel<<<zb, BLK, 0, stream>>>((float4*)rho_reps, n4);

        eam_density_rep<<<pair_blocks, BLK, 0, stream>>>(
            edge_i, edge_j, atom_types, positions,
            density_table, n_r, inv_dr, rclip, rho_reps, N, P);

        eam_rho_embed<<<atom_blocks, BLK, 0, stream>>>(
            rho_reps, atom_types, embed_deriv, embed_rho_min, embed_inv_drho,
            n_rho, one_m_eps, dF, N);

        eam_force_rep<<<pair_blocks, BLK, 0, stream>>>(
            edge_i, edge_j, atom_types, positions,
            density_deriv, pair_deriv, dF,
            n_r, E, inv_dr, rclip, force_reps, N, P);

        eam_force_reduce<<<(3 * N + BLK - 1) / BLK, BLK, 0, stream>>>(
            force_reps, forces, 3 * N);
    } else if (needB <= ws_size) {
        // Tier B: replicate rho only; forces via direct agent atomics
        float* dF       = (float*)d_ws;
        float* rho_reps = dF + Npad;                         // 8N

        long long n4 = (8LL * N) / 4;
        int zb = (int)((n4 + BLK - 1) / BLK);
        if (zb > 4096) zb = 4096;
        eam_zero4_kernel<<<zb, BLK, 0, stream>>>((float4*)rho_reps, n4);
        eam_zero_kernel<<<(3 * N + BLK - 1) / BLK, BLK, 0, stream>>>(forces, 3 * N);

        eam_density_rep<<<pair_blocks, BLK, 0, stream>>>(
            edge_i, edge_j, atom_types, positions,
            density_table, n_r, inv_dr, rclip, rho_reps, N, P);

        eam_rho_embed<<<atom_blocks, BLK, 0, stream>>>(
            rho_reps, atom_types, embed_deriv, embed_rho_min, embed_inv_drho,
            n_rho, one_m_eps, dF, N);

        eam_force_direct_dF<<<pair_blocks, BLK, 0, stream>>>(
            edge_i, edge_j, atom_types, positions,
            density_deriv, pair_deriv, dF,
            n_r, E, inv_dr, rclip, forces, P);
    } else {
        // Tier C: direct path (round-4)
        float* rho = (float*)d_ws;   // N floats
        eam_zero_kernel<<<atom_blocks, BLK, 0, stream>>>(rho, N);
        eam_zero_kernel<<<(3 * N + BLK - 1) / BLK, BLK, 0, stream>>>(forces, 3 * N);
        eam_density_direct<<<pair_blocks, BLK, 0, stream>>>(
            edge_i, edge_j, atom_types, positions,
            density_table, n_r, inv_dr, rclip, rho, P);
        eam_force_direct_embed<<<pair_blocks, BLK, 0, stream>>>(
            edge_i, edge_j, atom_types, positions,
            density_deriv, pair_deriv, rho,
            embed_deriv, embed_rho_min, embed_inv_drho,
            n_r, n_rho, E, inv_dr, rclip, one_m_eps, forces, P);
    }
}

// Round 8
// 917.027 us; speedup vs baseline: 2.7560x; 2.7366x over previous
//
#include <hip/hip_runtime.h>
#include <stdint.h>

// EAM force, atomic-free scatter via chunked bucket binning.
//
// HW model (r3-r7, four falsified alternatives): on gfx950 every global fp32
// atomic = one ~32B fabric transaction, draining ~20.5 G/s chip-wide,
// invariant to scope/address-spread/XCD-local replicas. Only fix: zero global
// fp atomics. Pairs -> (atom,value) records binned by 1024-atom bucket
// (per-block LDS counting sort; one int cursor atomic per block-bucket);
// per-bucket blocks accumulate records via LDS atomics and RMW the slab.
// Records region is sized from ws_size at runtime and processed in C chunks.
//
// ws: countD|countF|baseD|curD|baseF|curF [64*256 ints each] | rho[N] | dF[N]
//     | record region (one chunk at a time, reused D then F).

#define BLK     256
#define SHIFT   10
#define BSZ     1024
#define NBPAD   256
#define CMAX    64
#define PPB_CNT 2048
#define PPB_D   2048   // pairs/block, density bin (8/thread)
#define PPB_F   1024   // pairs/block, force bin   (4/thread)

__device__ __forceinline__ float interp_row(const float* __restrict__ row,
                                            int i0, int i1, float fr) {
    float a = row[i0];
    float b = row[i1];
    return a + fr * (b - a);
}

__device__ __forceinline__ float embed_dF_f(float rho, int t,
                                            const float* __restrict__ embed_tab,
                                            const float* __restrict__ rho_min_t,
                                            const float* __restrict__ inv_drho_t,
                                            int n_rho, float one_m_eps) {
    float rmin = rho_min_t[t];
    float invd = inv_drho_t[t];
    float hi = rmin + (float)(n_rho - 1) / invd * one_m_eps;
    float rc = fminf(fmaxf(rho, rmin), hi);
    float g  = (rc - rmin) * invd;
    int  g0  = (int)g;
    g0 = g0 < 0 ? 0 : (g0 > n_rho - 2 ? n_rho - 2 : g0);
    float gfr = g - (float)g0;
    const float* row = embed_tab + (size_t)t * n_rho;
    float e0 = row[g0];
    float e1 = row[g0 + 1];
    return e0 + gfr * (e1 - e0);
}

__device__ __forceinline__ void pair_geom(
    const float* __restrict__ pos, int i, int j,
    float inv_dr, float rclip,
    float& dx, float& dy, float& dz, float& r,
    int& i0, int& i1, float& fr, int n_r)
{
#pragma clang fp contract(off)
    float xi = pos[3 * i + 0], yi = pos[3 * i + 1], zi = pos[3 * i + 2];
    float xj = pos[3 * j + 0], yj = pos[3 * j + 1], zj = pos[3 * j + 2];
    dx = xj - xi; dy = yj - yi; dz = zj - zi;
    float s = dx * dx;
    s = s + dy * dy;
    s = s + dz * dz;
    s = s + 1e-12f;
    r = sqrtf(s);

    float rc = fminf(fmaxf(r, 0.0f), rclip);
    float f  = rc * inv_dr;
    i0 = (int)f;
    fr = f - (float)i0;
    i1 = min(i0 + 1, n_r - 1);
}

// ---------------- zero kernels ----------------

__global__ void eam_zero_ints(int* __restrict__ p, int n) {
    int idx = blockIdx.x * blockDim.x + threadIdx.x;
    int stride = gridDim.x * blockDim.x;
    for (; idx < n; idx += stride) p[idx] = 0;
}

__global__ void eam_zero_rho_forces(float* __restrict__ rho,
                                    float* __restrict__ forces, int N) {
    int idx = blockIdx.x * blockDim.x + threadIdx.x;
    if (idx < N) rho[idx] = 0.0f;
    if (idx < 3 * N) forces[idx] = 0.0f;
}

// ---------------- count & scan ----------------

__global__ void eam_count(const int* __restrict__ ei, const int* __restrict__ ej,
                          int P, int CH, int* __restrict__ counts /*[C][NBPAD]*/)
{
    __shared__ int cnt[NBPAD];
    for (int k = threadIdx.x; k < NBPAD; k += BLK) cnt[k] = 0;
    __syncthreads();
    long long start = (long long)blockIdx.x * PPB_CNT;   // within one chunk (CH % PPB_CNT == 0)
    int c = (int)(start / CH);
    int end = (int)((start + PPB_CNT < (long long)P) ? start + PPB_CNT : (long long)P);
    for (int p = (int)start + threadIdx.x; p < end; p += BLK) {
        atomicAdd(&cnt[((unsigned)ei[p]) >> SHIFT], 1);
        atomicAdd(&cnt[((unsigned)ej[p]) >> SHIFT], 1);
    }
    __syncthreads();
    int* gc = counts + (size_t)c * NBPAD;
    for (int k = threadIdx.x; k < NBPAD; k += BLK)
        if (cnt[k]) atomicAdd(&gc[k], cnt[k]);
}

__global__ void eam_scan(const int* __restrict__ counts,
                         int* __restrict__ base, int* __restrict__ cur, int C)
{
    __shared__ int s[NBPAD];
    int t = threadIdx.x;
    for (int c = 0; c < C; ++c) {
        int v = counts[c * NBPAD + t];
        s[t] = v;
        __syncthreads();
        for (int d = 1; d < NBPAD; d <<= 1) {
            int u = (t >= d) ? s[t - d] : 0;
            __syncthreads();
            s[t] += u;
            __syncthreads();
        }
        base[c * NBPAD + t] = s[t] - v;
        cur[c * NBPAD + t]  = s[t] - v;
        __syncthreads();
    }
}

// ---------------- density: bin + accumulate ----------------

__global__ __launch_bounds__(BLK) void eam_bin_density(
    const int* __restrict__ ei, const int* __restrict__ ej,
    const int* __restrict__ types, const float* __restrict__ pos,
    const float* __restrict__ dens_tab, int n_r, float inv_dr, float rclip,
    int p0, int pend,
    int* __restrict__ curc /* chunk cursors */,
    unsigned* __restrict__ recA, float* __restrict__ recV)
{
    __shared__ int cnt[NBPAD], off[NBPAD], cur[NBPAD], gb[NBPAD], sc[NBPAD];
    __shared__ unsigned sA[2 * PPB_D];
    __shared__ float    sV[2 * PPB_D];
    const int tid  = threadIdx.x;
    const int tile = p0 + blockIdx.x * PPB_D;

    for (int k = tid; k < NBPAD; k += BLK) cnt[k] = 0;
    __syncthreads();

    unsigned ra[16]; float rv[16]; bool valid[8];
#pragma unroll
    for (int k = 0; k < 8; ++k) {
        int p = tile + tid + k * BLK;
        valid[k] = (p < pend);
        unsigned i = 0, j = 0; float d_j = 0.f, d_i = 0.f;
        if (valid[k]) {
            i = (unsigned)ei[p]; j = (unsigned)ej[p];
            float dx, dy, dz, r, fr; int i0, i1;
            pair_geom(pos, (int)i, (int)j, inv_dr, rclip, dx, dy, dz, r, i0, i1, fr, n_r);
            int ti = types[i], tj = types[j];
            d_j = interp_row(dens_tab + (size_t)tj * n_r, i0, i1, fr);
            d_i = interp_row(dens_tab + (size_t)ti * n_r, i0, i1, fr);
            atomicAdd(&cnt[i >> SHIFT], 1);
            atomicAdd(&cnt[j >> SHIFT], 1);
        }
        ra[2 * k] = i;     rv[2 * k] = d_j;
        ra[2 * k + 1] = j; rv[2 * k + 1] = d_i;
    }
    __syncthreads();

    int c = cnt[tid];
    sc[tid] = c;
    __syncthreads();
    for (int d = 1; d < NBPAD; d <<= 1) {
        int v = (tid >= d) ? sc[tid - d] : 0;
        __syncthreads();
        sc[tid] += v;
        __syncthreads();
    }
    int o = sc[tid] - c;
    off[tid] = o; cur[tid] = o;
    if (c > 0) gb[tid] = atomicAdd(&curc[tid], c);
    __syncthreads();

#pragma unroll
    for (int k = 0; k < 8; ++k) if (valid[k]) {
#pragma unroll
        for (int s2 = 0; s2 < 2; ++s2) {
            unsigned a = ra[2 * k + s2];
            int b = a >> SHIFT;
            int sl = atomicAdd(&cur[b], 1);
            sA[sl] = a; sV[sl] = rv[2 * k + s2];
        }
    }
    __syncthreads();

    int total = off[NBPAD - 1] + cnt[NBPAD - 1];
    for (int s2 = tid; s2 < total; s2 += BLK) {
        unsigned a = sA[s2];
        int b = a >> SHIFT;
        int dst = gb[b] + (s2 - off[b]);
        recA[dst] = a; recV[dst] = sV[s2];
    }
}

__global__ __launch_bounds__(BLK) void eam_acc_density(
    const unsigned* __restrict__ recA, const float* __restrict__ recV,
    const int* __restrict__ basec, const int* __restrict__ countc,
    float* __restrict__ rho, int N)
{
    __shared__ float acc[BSZ];
    int b = blockIdx.x;
    int abase = b << SHIFT;
    for (int k = threadIdx.x; k < BSZ; k += BLK) {
        int a = abase + k;
        acc[k] = (a < N) ? rho[a] : 0.0f;
    }
    __syncthreads();
    int s = basec[b], e = s + countc[b];
    for (int q = s + threadIdx.x; q < e; q += BLK)
        atomicAdd(&acc[recA[q] & (BSZ - 1)], recV[q]);
    __syncthreads();
    for (int k = threadIdx.x; k < BSZ; k += BLK) {
        int a = abase + k;
        if (a < N) rho[a] = acc[k];
    }
}

// ---------------- embed (per atom) ----------------

__global__ void eam_embed(const float* __restrict__ rho, const int* __restrict__ types,
                          const float* __restrict__ embed_tab,
                          const float* __restrict__ rho_min_t,
                          const float* __restrict__ inv_drho_t,
                          int n_rho, float one_m_eps, float* __restrict__ dF, int N)
{
    int n = blockIdx.x * blockDim.x + threadIdx.x;
    if (n >= N) return;
    dF[n] = embed_dF_f(rho[n], types[n], embed_tab, rho_min_t, inv_drho_t,
                       n_rho, one_m_eps);
}

// ---------------- force: bin + accumulate ----------------

__global__ __launch_bounds__(BLK) void eam_bin_force(
    const int* __restrict__ ei, const int* __restrict__ ej,
    const int* __restrict__ types, const float* __restrict__ pos,
    const float* __restrict__ dens_deriv_tab,
    const float* __restrict__ pair_deriv_tab,
    const float* __restrict__ dF,
    int n_r, int E, float inv_dr, float rclip,
    int p0, int pend,
    int* __restrict__ curc,
    unsigned* __restrict__ recA,
    float* __restrict__ recX, float* __restrict__ recY, float* __restrict__ recZ)
{
    __shared__ int cnt[NBPAD], off[NBPAD], cur[NBPAD], gb[NBPAD], sc[NBPAD];
    __shared__ unsigned sA[2 * PPB_F];
    __shared__ float sX[2 * PPB_F], sY[2 * PPB_F], sZ[2 * PPB_F];
    const int tid  = threadIdx.x;
    const int tile = p0 + blockIdx.x * PPB_F;

    for (int k = tid; k < NBPAD; k += BLK) cnt[k] = 0;
    __syncthreads();

    unsigned ia[4], ja[4];
    float fx[4], fy[4], fz[4];
    bool valid[4];
#pragma unroll
    for (int k = 0; k < 4; ++k) {
        int p = tile + tid + k * BLK;
        valid[k] = (p < pend);
        unsigned i = 0, j = 0; float vx = 0.f, vy = 0.f, vz = 0.f;
        if (valid[k]) {
            i = (unsigned)ei[p]; j = (unsigned)ej[p];
            float dx, dy, dz, r, fr; int i0, i1;
            pair_geom(pos, (int)i, (int)j, inv_dr, rclip, dx, dy, dz, r, i0, i1, fr, n_r);
            int ti = types[i], tj = types[j];
            float ddens_j = interp_row(dens_deriv_tab + (size_t)tj * n_r, i0, i1, fr);
            float ddens_i = interp_row(dens_deriv_tab + (size_t)ti * n_r, i0, i1, fr);
            float dphi    = interp_row(pair_deriv_tab + ((size_t)ti * E + tj) * n_r, i0, i1, fr);
            float coeff = dF[i] * ddens_j + dF[j] * ddens_i + dphi;
            vx = coeff * (dx / r);
            vy = coeff * (dy / r);
            vz = coeff * (dz / r);
            atomicAdd(&cnt[i >> SHIFT], 1);
            atomicAdd(&cnt[j >> SHIFT], 1);
        }
        ia[k] = i; ja[k] = j; fx[k] = vx; fy[k] = vy; fz[k] = vz;
    }
    __syncthreads();

    int c = cnt[tid];
    sc[tid] = c;
    __syncthreads();
    for (int d = 1; d < NBPAD; d <<= 1) {
        int v = (tid >= d) ? sc[tid - d] : 0;
        __syncthreads();
        sc[tid] += v;
        __syncthreads();
    }
    int o = sc[tid] - c;
    off[tid] = o; cur[tid] = o;
    if (c > 0) gb[tid] = atomicAdd(&curc[tid], c);
    __syncthreads();

#pragma unroll
    for (int k = 0; k < 4; ++k) if (valid[k]) {
        {
            unsigned a = ia[k];
            int b = a >> SHIFT;
            int sl = atomicAdd(&cur[b], 1);
            sA[sl] = a; sX[sl] = -fx[k]; sY[sl] = -fy[k]; sZ[sl] = -fz[k];
        }
        {
            unsigned a = ja[k];
            int b = a >> SHIFT;
            int sl = atomicAdd(&cur[b], 1);
            sA[sl] = a; sX[sl] = fx[k]; sY[sl] = fy[k]; sZ[sl] = fz[k];
        }
    }
    __syncthreads();

    int total = off[NBPAD - 1] + cnt[NBPAD - 1];
    for (int s2 = tid; s2 < total; s2 += BLK) {
        unsigned a = sA[s2];
        int b = a >> SHIFT;
        int dst = gb[b] + (s2 - off[b]);
        recA[dst] = a;
        recX[dst] = sX[s2];
        recY[dst] = sY[s2];
        recZ[dst] = sZ[s2];
    }
}

__global__ __launch_bounds__(BLK) void eam_acc_force(
    const unsigned* __restrict__ recA,
    const float* __restrict__ recX, const float* __restrict__ recY,
    const float* __restrict__ recZ,
    const int* __restrict__ basec, const int* __restrict__ countc,
    float* __restrict__ forces, int N)
{
    __shared__ float acc[3 * BSZ];
    int b = blockIdx.x;
    int abase = b << SHIFT;
    int lim = 3 * (N - abase);
    if (lim > 3 * BSZ) lim = 3 * BSZ;
    for (int k = threadIdx.x; k < lim; k += BLK)
        acc[k] = forces[3 * abase + k];
    __syncthreads();
    int s = basec[b], e = s + countc[b];
    for (int q = s + threadIdx.x; q < e; q += BLK) {
        int loc = (int)(recA[q] & (BSZ - 1)) * 3;
        atomicAdd(&acc[loc + 0], recX[q]);
        atomicAdd(&acc[loc + 1], recY[q]);
        atomicAdd(&acc[loc + 2], recZ[q]);
    }
    __syncthreads();
    for (int k = threadIdx.x; k < lim; k += BLK)
        forces[3 * abase + k] = acc[k];
}

// ---------------- fallback: direct agent-atomic path (r4, proven) ----------------

__global__ void eam_density_direct(
    const int* __restrict__ ei, const int* __restrict__ ej,
    const int* __restrict__ types, const float* __restrict__ pos,
    const float* __restrict__ dens_tab, int n_r, float inv_dr, float rclip,
    float* __restrict__ rho, int P)
{
    int p = blockIdx.x * blockDim.x + threadIdx.x;
    if (p >= P) return;
    int i = ei[p], j = ej[p];
    float dx, dy, dz, r, fr; int i0, i1;
    pair_geom(pos, i, j, inv_dr, rclip, dx, dy, dz, r, i0, i1, fr, n_r);
    int ti = types[i], tj = types[j];
    unsafeAtomicAdd(&rho[i], interp_row(dens_tab + (size_t)tj * n_r, i0, i1, fr));
    unsafeAtomicAdd(&rho[j], interp_row(dens_tab + (size_t)ti * n_r, i0, i1, fr));
}

__global__ void eam_force_direct(
    const int* __restrict__ ei, const int* __restrict__ ej,
    const int* __restrict__ types, const float* __restrict__ pos,
    const float* __restrict__ dens_deriv_tab,
    const float* __restrict__ pair_deriv_tab,
    const float* __restrict__ rho,
    const float* __restrict__ embed_tab,
    const float* __restrict__ rho_min_t, const float* __restrict__ inv_drho_t,
    int n_r, int n_rho, int E, float inv_dr, float rclip, float one_m_eps,
    float* __restrict__ forces, int P)
{
    int p = blockIdx.x * blockDim.x + threadIdx.x;
    if (p >= P) return;
    int i = ei[p], j = ej[p];
    float dx, dy, dz, r, fr; int i0, i1;
    pair_geom(pos, i, j, inv_dr, rclip, dx, dy, dz, r, i0, i1, fr, n_r);
    int ti = types[i], tj = types[j];
    float ddens_j = interp_row(dens_deriv_tab + (size_t)tj * n_r, i0, i1, fr);
    float ddens_i = interp_row(dens_deriv_tab + (size_t)ti * n_r, i0, i1, fr);
    float dphi    = interp_row(pair_deriv_tab + ((size_t)ti * E + tj) * n_r, i0, i1, fr);
    float dFi = embed_dF_f(rho[i], ti, embed_tab, rho_min_t, inv_drho_t, n_rho, one_m_eps);
    float dFj = embed_dF_f(rho[j], tj, embed_tab, rho_min_t, inv_drho_t, n_rho, one_m_eps);
    float coeff = dFi * ddens_j + dFj * ddens_i + dphi;
    float fxv = coeff * (dx / r), fyv = coeff * (dy / r), fzv = coeff * (dz / r);
    unsafeAtomicAdd(&forces[3 * i + 0], -fxv);
    unsafeAtomicAdd(&forces[3 * i + 1], -fyv);
    unsafeAtomicAdd(&forces[3 * i + 2], -fzv);
    unsafeAtomicAdd(&forces[3 * j + 0],  fxv);
    unsafeAtomicAdd(&forces[3 * j + 1],  fyv);
    unsafeAtomicAdd(&forces[3 * j + 2],  fzv);
}

// ---------------- launcher ----------------

extern "C" void kernel_launch(void* const* d_in, const int* in_sizes, int n_in,
                              void* d_out, int out_size, void* d_ws, size_t ws_size,
                              hipStream_t stream) {
    const float* positions      = (const float*)d_in[0];
    const float* density_table  = (const float*)d_in[1];
    const float* density_deriv  = (const float*)d_in[2];
    const float* pair_deriv     = (const float*)d_in[3];
    const float* embed_deriv    = (const float*)d_in[4];
    const float* embed_rho_min  = (const float*)d_in[5];
    const float* embed_inv_drho = (const float*)d_in[6];
    const int*   atom_types     = (const int*)d_in[7];
    const int*   edge_i         = (const int*)d_in[8];
    const int*   edge_j         = (const int*)d_in[9];

    const int E     = in_sizes[5];
    const int N     = in_sizes[7];
    const int P     = in_sizes[8];
    const int n_r   = in_sizes[1] / E;
    const int n_rho = in_sizes[4] / E;

    const double R_MAX_d = 6.0;
    const double EPS_d   = 1e-7;
    const float inv_dr    = (float)((double)(n_r - 1) / R_MAX_d);
    const float rclip     = (float)(R_MAX_d * (1.0 - EPS_d));
    const float one_m_eps = (float)(1.0 - EPS_d);

    float* forces = (float*)d_out;

    const int NB = (N + BSZ - 1) >> SHIFT;
    const size_t Npad = ((size_t)N + 3) & ~(size_t)3;

    // meta layout: countD | countF | baseD | curD | baseF | curF
    const size_t MI = (size_t)CMAX * NBPAD;
    char* wp = (char*)d_ws;
    int* countD = (int*)wp;  wp += MI * sizeof(int);
    int* countF = (int*)wp;  wp += MI * sizeof(int);
    int* baseD  = (int*)wp;  wp += MI * sizeof(int);
    int* curD   = (int*)wp;  wp += MI * sizeof(int);
    int* baseF  = (int*)wp;  wp += MI * sizeof(int);
    int* curF   = (int*)wp;  wp += MI * sizeof(int);
    float* rho  = (float*)wp; wp += Npad * sizeof(float);
    float* dF   = (float*)wp; wp += Npad * sizeof(float);
    char* rec   = wp;
    const size_t fixed = (size_t)(rec - (char*)d_ws);

    long long availLL = (long long)ws_size - (long long)fixed;
    long long CH_D = 0, CH_F = 0;
    int C_D = CMAX + 1, C_F = CMAX + 1;
    if (availLL > 0) {
        size_t avail = (size_t)availLL;
        CH_D = (long long)((avail / 16) & ~(size_t)(PPB_CNT - 1)); // 2 recs x 8B /pair
        CH_F = (long long)((avail / 32) & ~(size_t)(PPB_CNT - 1)); // 2 recs x 16B/pair
        if (CH_D > P) CH_D = ((long long)P + PPB_CNT - 1) & ~(long long)(PPB_CNT - 1);
        if (CH_F > P) CH_F = ((long long)P + PPB_CNT - 1) & ~(long long)(PPB_CNT - 1);
        if (CH_D >= PPB_CNT) C_D = (int)((P + CH_D - 1) / CH_D);
        if (CH_F >= PPB_CNT) C_F = (int)((P + CH_F - 1) / CH_F);
    }

    const int pair_blocks = (P + BLK - 1) / BLK;
    const int atom_blocks = (N + BLK - 1) / BLK;
    const int zf_blocks   = (3 * N + BLK - 1) / BLK;

    if (C_D > CMAX || C_F > CMAX || NB > NBPAD) {
        // fallback: direct agent-atomic path (r4 behavior, 2.51 ms)
        float* rho_f = (float*)d_ws;
        eam_zero_rho_forces<<<zf_blocks, BLK, 0, stream>>>(rho_f, forces, N);
        eam_density_direct<<<pair_blocks, BLK, 0, stream>>>(
            edge_i, edge_j, atom_types, positions,
            density_table, n_r, inv_dr, rclip, rho_f, P);
        eam_force_direct<<<pair_blocks, BLK, 0, stream>>>(
            edge_i, edge_j, atom_types, positions,
            density_deriv, pair_deriv, rho_f,
            embed_deriv, embed_rho_min, embed_inv_drho,
            n_r, n_rho, E, inv_dr, rclip, one_m_eps, forces, P);
        return;
    }

    // record arrays (chunk-local, region reused by D then F phase)
    unsigned* recA_D = (unsigned*)rec;
    float*    recV_D = (float*)(rec + 8ll * CH_D);
    unsigned* recA_F = (unsigned*)rec;
    float*    recX   = (float*)(rec + 8ll * CH_F);
    float*    recY   = (float*)(rec + 16ll * CH_F);
    float*    recZ   = (float*)(rec + 24ll * CH_F);

    // zero meta counts + rho + forces
    eam_zero_ints<<<64, BLK, 0, stream>>>(countD, (int)(2 * MI));
    eam_zero_rho_forces<<<zf_blocks, BLK, 0, stream>>>(rho, forces, N);

    const int cnt_blocks = (P + PPB_CNT - 1) / PPB_CNT;
    eam_count<<<cnt_blocks, BLK, 0, stream>>>(edge_i, edge_j, P, (int)CH_D, countD);
    eam_count<<<cnt_blocks, BLK, 0, stream>>>(edge_i, edge_j, P, (int)CH_F, countF);
    eam_scan<<<1, NBPAD, 0, stream>>>(countD, baseD, curD, C_D);
    eam_scan<<<1, NBPAD, 0, stream>>>(countF, baseF, curF, C_F);

    // ---- density phase ----
    for (int c = 0; c < C_D; ++c) {
        int p0 = (int)((long long)c * CH_D);
        int pe = (int)((long long)(c + 1) * CH_D < P ? (long long)(c + 1) * CH_D : P);
        int nb = (pe - p0 + PPB_D - 1) / PPB_D;
        eam_bin_density<<<nb, BLK, 0, stream>>>(
            edge_i, edge_j, atom_types, positions,
            density_table, n_r, inv_dr, rclip,
            p0, pe, curD + (size_t)c * NBPAD, recA_D, recV_D);
        eam_acc_density<<<NB, BLK, 0, stream>>>(
            recA_D, recV_D, baseD + (size_t)c * NBPAD, countD + (size_t)c * NBPAD,
            rho, N);
    }

    eam_embed<<<atom_blocks, BLK, 0, stream>>>(
        rho, atom_types, embed_deriv, embed_rho_min, embed_inv_drho,
        n_rho, one_m_eps, dF, N);

    // ---- force phase ----
    for (int c = 0; c < C_F; ++c) {
        int p0 = (int)((long long)c * CH_F);
        int pe = (int)((long long)(c + 1) * CH_F < P ? (long long)(c + 1) * CH_F : P);
        int nb = (pe - p0 + PPB_F - 1) / PPB_F;
        eam_bin_force<<<nb, BLK, 0, stream>>>(
            edge_i, edge_j, atom_types, positions,
            density_deriv, pair_deriv, dF,
            n_r, E, inv_dr, rclip,
            p0, pe, curF + (size_t)c * NBPAD,
            recA_F, recX, recY, recZ);
        eam_acc_force<<<NB, BLK, 0, stream>>>(
            recA_F, recX, recY, recZ,
            baseF + (size_t)c * NBPAD, countF + (size_t)c * NBPAD,
            forces, N);
    }
}

// Round 9
// 491.962 us; speedup vs baseline: 5.1373x; 1.8640x over previous
//
#include <hip/hip_runtime.h>
#include <stdint.h>

// EAM force via index-only CSR binning (built once, used twice).
//
// HW model (r3-r7): global fp32 atomics = ~32B fabric transaction each,
// ~20.5G/s chip-wide, invariant to scope/spread/XCD-locality -> use none.
// r8 (917us) showed value-records dominate: 307MB written + 307MB read + RMW
// amplification, and acc kernels ran only 196 blocks.
// Fix: one 4B directed record per pair-endpoint:
//   rec = other_idx(20b) | owner_low10(10b) | orient(1b), sorted by
//   1024-atom owner bucket. Both phases recompute geometry from L2-resident
//   pos/types/dF/tables (bitwise-identical per contribution; exact negation
//   and IEEE-commutative adds; only summation order differs).
// Acc phases: 8 strip-blocks per bucket, LDS slab accumulate -> partial
// slabs -> tiny reduce. Zero global fp atomics.

#define BLK     256
#define SHIFT   10
#define BSZ     1024
#define NBPAD   256
#define SSTRIPS 8
#define PPB_B   4096   // pairs per bin block (two-pass, 8192 records LDS)

__device__ __forceinline__ float interp_row(const float* __restrict__ row,
                                            int i0, int i1, float fr) {
    float a = row[i0];
    float b = row[i1];
    return a + fr * (b - a);
}

__device__ __forceinline__ float embed_dF_f(float rho, int t,
                                            const float* __restrict__ embed_tab,
                                            const float* __restrict__ rho_min_t,
                                            const float* __restrict__ inv_drho_t,
                                            int n_rho, float one_m_eps) {
    float rmin = rho_min_t[t];
    float invd = inv_drho_t[t];
    float hi = rmin + (float)(n_rho - 1) / invd * one_m_eps;
    float rc = fminf(fmaxf(rho, rmin), hi);
    float g  = (rc - rmin) * invd;
    int  g0  = (int)g;
    g0 = g0 < 0 ? 0 : (g0 > n_rho - 2 ? n_rho - 2 : g0);
    float gfr = g - (float)g0;
    const float* row = embed_tab + (size_t)t * n_rho;
    float e0 = row[g0];
    float e1 = row[g0 + 1];
    return e0 + gfr * (e1 - e0);
}

// owner-centric r-index; bitwise matches reference for both orientations
__device__ __forceinline__ void geom_own(
    float xo, float yo, float zo,      // other
    float xw, float yw, float zw,      // owner
    float inv_dr, float rclip, int n_r,
    float& dx, float& dy, float& dz, float& r,
    int& i0, int& i1, float& fr)
{
#pragma clang fp contract(off)
    dx = xo - xw; dy = yo - yw; dz = zo - zw;
    float s = dx * dx;
    s = s + dy * dy;
    s = s + dz * dz;
    s = s + 1e-12f;
    r = sqrtf(s);
    float rc = fminf(fmaxf(r, 0.0f), rclip);
    float f  = rc * inv_dr;
    i0 = (int)f;
    fr = f - (float)i0;
    i1 = min(i0 + 1, n_r - 1);
}

// ---------------- meta ----------------

__global__ void eam_zero_meta(int* __restrict__ counts) {
    counts[threadIdx.x] = 0;
}

__global__ void eam_count(const int* __restrict__ ei, const int* __restrict__ ej,
                          int P, int* __restrict__ counts)
{
    __shared__ int cnt[NBPAD];
    for (int k = threadIdx.x; k < NBPAD; k += BLK) cnt[k] = 0;
    __syncthreads();
    for (int p = blockIdx.x * BLK + threadIdx.x; p < P; p += gridDim.x * BLK) {
        atomicAdd(&cnt[((unsigned)ei[p]) >> SHIFT], 1);
        atomicAdd(&cnt[((unsigned)ej[p]) >> SHIFT], 1);
    }
    __syncthreads();
    for (int k = threadIdx.x; k < NBPAD; k += BLK)
        if (cnt[k]) atomicAdd(&counts[k], cnt[k]);
}

__global__ void eam_scan(const int* __restrict__ counts,
                         int* __restrict__ base, int* __restrict__ cur)
{
    __shared__ int s[NBPAD];
    int t = threadIdx.x;
    int c = counts[t];
    s[t] = c;
    __syncthreads();
    for (int d = 1; d < NBPAD; d <<= 1) {
        int v = (t >= d) ? s[t - d] : 0;
        __syncthreads();
        s[t] += v;
        __syncthreads();
    }
    base[t] = s[t] - c;
    cur[t]  = s[t] - c;
}

// ---------------- bin: build directed index records ----------------

__global__ __launch_bounds__(BLK) void eam_bin(
    const int* __restrict__ ei, const int* __restrict__ ej, int P,
    int* __restrict__ cur_glob, unsigned* __restrict__ recs)
{
    __shared__ int cnt[NBPAD], off[NBPAD], curs[NBPAD], gb[NBPAD], sc[NBPAD];
    __shared__ unsigned sR[2 * PPB_B];
    __shared__ unsigned char sB[2 * PPB_B];
    const int tid = threadIdx.x;
    const long long p0 = (long long)blockIdx.x * PPB_B;
    const int pend = (int)((p0 + PPB_B < (long long)P) ? p0 + PPB_B : (long long)P);

    for (int k = tid; k < NBPAD; k += BLK) cnt[k] = 0;
    __syncthreads();

    // pass 1: count
    for (int p = (int)p0 + tid; p < pend; p += BLK) {
        atomicAdd(&cnt[((unsigned)ei[p]) >> SHIFT], 1);
        atomicAdd(&cnt[((unsigned)ej[p]) >> SHIFT], 1);
    }
    __syncthreads();

    // block-local scan + global reservation
    int c = cnt[tid];
    sc[tid] = c;
    __syncthreads();
    for (int d = 1; d < NBPAD; d <<= 1) {
        int v = (tid >= d) ? sc[tid - d] : 0;
        __syncthreads();
        sc[tid] += v;
        __syncthreads();
    }
    off[tid] = sc[tid] - c;
    curs[tid] = off[tid];
    if (c > 0) gb[tid] = atomicAdd(&cur_glob[tid], c);
    __syncthreads();

    // pass 2: place records into LDS, grouped by bucket
    for (int p = (int)p0 + tid; p < pend; p += BLK) {
        unsigned i = (unsigned)ei[p];
        unsigned j = (unsigned)ej[p];
        int bi = i >> SHIFT;
        int sl = atomicAdd(&curs[bi], 1);
        sR[sl] = j | ((i & (BSZ - 1)) << 20) | (1u << 30);  // owner=i (edge_i)
        sB[sl] = (unsigned char)bi;
        int bj = j >> SHIFT;
        sl = atomicAdd(&curs[bj], 1);
        sR[sl] = i | ((j & (BSZ - 1)) << 20);               // owner=j
        sB[sl] = (unsigned char)bj;
    }
    __syncthreads();

    // coalesced segment write-out
    int total = off[NBPAD - 1] + cnt[NBPAD - 1];
    for (int q = tid; q < total; q += BLK) {
        int b = sB[q];
        int dst = gb[b] + (q - off[b]);
        recs[dst] = sR[q];
    }
}

// ---------------- acc rho (strips, LDS slab, partial out) ----------------

__global__ __launch_bounds__(BLK) void eam_acc_rho(
    const unsigned* __restrict__ recs,
    const int* __restrict__ base, const int* __restrict__ counts,
    const float* __restrict__ pos, const int* __restrict__ types,
    const float* __restrict__ dens_tab, int n_r, float inv_dr, float rclip,
    float* __restrict__ partial, int N)
{
    __shared__ float4 sposT[BSZ];
    __shared__ float slab[BSZ];
    const int tid = threadIdx.x;
    const int b = blockIdx.x >> 3;
    const int s = blockIdx.x & 7;
    const int abase = b << SHIFT;

    for (int k = tid; k < BSZ; k += BLK) {
        int a = abase + k;
        float4 v = make_float4(0.f, 0.f, 0.f, 0.f);
        if (a < N) {
            v.x = pos[3 * a + 0];
            v.y = pos[3 * a + 1];
            v.z = pos[3 * a + 2];
        }
        sposT[k] = v;
        slab[k] = 0.f;
    }
    __syncthreads();

    int cb = counts[b];
    int e0 = base[b] + (int)(((long long)cb * s) / SSTRIPS);
    int e1 = base[b] + (int)(((long long)cb * (s + 1)) / SSTRIPS);

    for (int q = e0 + tid; q < e1; q += BLK) {
        unsigned rec = recs[q];
        int other = rec & 0xFFFFF;
        int low = (rec >> 20) & (BSZ - 1);
        float4 w = sposT[low];
        float xo = pos[3 * other + 0];
        float yo = pos[3 * other + 1];
        float zo = pos[3 * other + 2];
        float dx, dy, dz, r, fr; int i0, i1;
        geom_own(xo, yo, zo, w.x, w.y, w.z, inv_dr, rclip, n_r,
                 dx, dy, dz, r, i0, i1, fr);
        int t_oth = types[other];
        float v = interp_row(dens_tab + (size_t)t_oth * n_r, i0, i1, fr);
        atomicAdd(&slab[low], v);
    }
    __syncthreads();

    float* out = partial + ((size_t)(b * SSTRIPS + s) << SHIFT);
    for (int k = tid; k < BSZ; k += BLK) out[k] = slab[k];
}

__global__ void eam_reduce_rho_embed(
    const float* __restrict__ partial, const int* __restrict__ types,
    const float* __restrict__ embed_tab,
    const float* __restrict__ rho_min_t, const float* __restrict__ inv_drho_t,
    int n_rho, float one_m_eps, float* __restrict__ dF, int N)
{
    int n = blockIdx.x * blockDim.x + threadIdx.x;
    if (n >= N) return;
    int b = n >> SHIFT;
    int low = n & (BSZ - 1);
    float rho = 0.f;
#pragma unroll
    for (int s = 0; s < SSTRIPS; ++s)
        rho += partial[((size_t)(b * SSTRIPS + s) << SHIFT) + low];
    dF[n] = embed_dF_f(rho, types[n], embed_tab, rho_min_t, inv_drho_t,
                       n_rho, one_m_eps);
}

// ---------------- acc force (strips, LDS slab, partial out) ----------------

__global__ __launch_bounds__(BLK) void eam_acc_force(
    const unsigned* __restrict__ recs,
    const int* __restrict__ base, const int* __restrict__ counts,
    const float* __restrict__ pos, const int* __restrict__ types,
    const float* __restrict__ dF,
    const float* __restrict__ dens_deriv_tab,
    const float* __restrict__ pair_deriv_tab,
    int n_r, int E, float inv_dr, float rclip,
    float* __restrict__ partial, int N)
{
    __shared__ float4 sposT[BSZ];   // xyz + type-as-float
    __shared__ float sdF[BSZ];
    __shared__ float slab[3 * BSZ];
    const int tid = threadIdx.x;
    const int b = blockIdx.x >> 3;
    const int s = blockIdx.x & 7;
    const int abase = b << SHIFT;

    for (int k = tid; k < BSZ; k += BLK) {
        int a = abase + k;
        float4 v = make_float4(0.f, 0.f, 0.f, __int_as_float(0));
        float df = 0.f;
        if (a < N) {
            v.x = pos[3 * a + 0];
            v.y = pos[3 * a + 1];
            v.z = pos[3 * a + 2];
            v.w = __int_as_float(types[a]);
            df = dF[a];
        }
        sposT[k] = v;
        sdF[k] = df;
    }
    for (int k = tid; k < 3 * BSZ; k += BLK) slab[k] = 0.f;
    __syncthreads();

    int cb = counts[b];
    int e0 = base[b] + (int)(((long long)cb * s) / SSTRIPS);
    int e1 = base[b] + (int)(((long long)cb * (s + 1)) / SSTRIPS);

    for (int q = e0 + tid; q < e1; q += BLK) {
        unsigned rec = recs[q];
        int other  = rec & 0xFFFFF;
        int low    = (rec >> 20) & (BSZ - 1);
        int orient = (rec >> 30) & 1;

        float4 w = sposT[low];
        int   t_own = __float_as_int(w.w);
        float dF_own = sdF[low];

        float xo = pos[3 * other + 0];
        float yo = pos[3 * other + 1];
        float zo = pos[3 * other + 2];
        int   t_oth = types[other];
        float dF_oth = dF[other];

        float dx, dy, dz, r, fr; int i0, i1;
        geom_own(xo, yo, zo, w.x, w.y, w.z, inv_dr, rclip, n_r,
                 dx, dy, dz, r, i0, i1, fr);

        float ddens_oth = interp_row(dens_deriv_tab + (size_t)t_oth * n_r, i0, i1, fr);
        float ddens_own = interp_row(dens_deriv_tab + (size_t)t_own * n_r, i0, i1, fr);
        int prow = orient ? (t_own * E + t_oth) : (t_oth * E + t_own);
        float dphi = interp_row(pair_deriv_tab + (size_t)prow * n_r, i0, i1, fr);

        float coeff = dF_own * ddens_oth + dF_oth * ddens_own + dphi;

        // contribution to owner = -coeff * (d'/r), bitwise == reference
        float fx = -(coeff * (dx / r));
        float fy = -(coeff * (dy / r));
        float fz = -(coeff * (dz / r));

        atomicAdd(&slab[low * 3 + 0], fx);
        atomicAdd(&slab[low * 3 + 1], fy);
        atomicAdd(&slab[low * 3 + 2], fz);
    }
    __syncthreads();

    float* out = partial + (size_t)(b * SSTRIPS + s) * (3 * BSZ);
    for (int k = tid; k < 3 * BSZ; k += BLK) out[k] = slab[k];
}

__global__ void eam_reduce_force(const float* __restrict__ partial,
                                 float* __restrict__ forces, int N)
{
    int idx = blockIdx.x * blockDim.x + threadIdx.x;
    if (idx >= 3 * N) return;
    int a = idx / 3;
    int comp = idx - 3 * a;
    int b = a >> SHIFT;
    int low = a & (BSZ - 1);
    float s = 0.f;
#pragma unroll
    for (int k = 0; k < SSTRIPS; ++k)
        s += partial[(size_t)(b * SSTRIPS + k) * (3 * BSZ) + low * 3 + comp];
    forces[idx] = s;
}

// ---------------- fallback: direct agent-atomic path (r4, proven) ----------------

__device__ __forceinline__ void pair_geom(
    const float* __restrict__ pos, int i, int j,
    float inv_dr, float rclip,
    float& dx, float& dy, float& dz, float& r,
    int& i0, int& i1, float& fr, int n_r)
{
#pragma clang fp contract(off)
    float xi = pos[3 * i + 0], yi = pos[3 * i + 1], zi = pos[3 * i + 2];
    float xj = pos[3 * j + 0], yj = pos[3 * j + 1], zj = pos[3 * j + 2];
    dx = xj - xi; dy = yj - yi; dz = zj - zi;
    float s = dx * dx;
    s = s + dy * dy;
    s = s + dz * dz;
    s = s + 1e-12f;
    r = sqrtf(s);
    float rc = fminf(fmaxf(r, 0.0f), rclip);
    float f  = rc * inv_dr;
    i0 = (int)f;
    fr = f - (float)i0;
    i1 = min(i0 + 1, n_r - 1);
}

__global__ void eam_zero_rho_forces(float* __restrict__ rho,
                                    float* __restrict__ forces, int N) {
    int idx = blockIdx.x * blockDim.x + threadIdx.x;
    if (idx < N) rho[idx] = 0.0f;
    if (idx < 3 * N) forces[idx] = 0.0f;
}

__global__ void eam_density_direct(
    const int* __restrict__ ei, const int* __restrict__ ej,
    const int* __restrict__ types, const float* __restrict__ pos,
    const float* __restrict__ dens_tab, int n_r, float inv_dr, float rclip,
    float* __restrict__ rho, int P)
{
    int p = blockIdx.x * blockDim.x + threadIdx.x;
    if (p >= P) return;
    int i = ei[p], j = ej[p];
    float dx, dy, dz, r, fr; int i0, i1;
    pair_geom(pos, i, j, inv_dr, rclip, dx, dy, dz, r, i0, i1, fr, n_r);
    int ti = types[i], tj = types[j];
    unsafeAtomicAdd(&rho[i], interp_row(dens_tab + (size_t)tj * n_r, i0, i1, fr));
    unsafeAtomicAdd(&rho[j], interp_row(dens_tab + (size_t)ti * n_r, i0, i1, fr));
}

__global__ void eam_force_direct(
    const int* __restrict__ ei, const int* __restrict__ ej,
    const int* __restrict__ types, const float* __restrict__ pos,
    const float* __restrict__ dens_deriv_tab,
    const float* __restrict__ pair_deriv_tab,
    const float* __restrict__ rho,
    const float* __restrict__ embed_tab,
    const float* __restrict__ rho_min_t, const float* __restrict__ inv_drho_t,
    int n_r, int n_rho, int E, float inv_dr, float rclip, float one_m_eps,
    float* __restrict__ forces, int P)
{
    int p = blockIdx.x * blockDim.x + threadIdx.x;
    if (p >= P) return;
    int i = ei[p], j = ej[p];
    float dx, dy, dz, r, fr; int i0, i1;
    pair_geom(pos, i, j, inv_dr, rclip, dx, dy, dz, r, i0, i1, fr, n_r);
    int ti = types[i], tj = types[j];
    float ddens_j = interp_row(dens_deriv_tab + (size_t)tj * n_r, i0, i1, fr);
    float ddens_i = interp_row(dens_deriv_tab + (size_t)ti * n_r, i0, i1, fr);
    float dphi    = interp_row(pair_deriv_tab + ((size_t)ti * E + tj) * n_r, i0, i1, fr);
    float dFi = embed_dF_f(rho[i], ti, embed_tab, rho_min_t, inv_drho_t, n_rho, one_m_eps);
    float dFj = embed_dF_f(rho[j], tj, embed_tab, rho_min_t, inv_drho_t, n_rho, one_m_eps);
    float coeff = dFi * ddens_j + dFj * ddens_i + dphi;
    float fxv = coeff * (dx / r), fyv = coeff * (dy / r), fzv = coeff * (dz / r);
    unsafeAtomicAdd(&forces[3 * i + 0], -fxv);
    unsafeAtomicAdd(&forces[3 * i + 1], -fyv);
    unsafeAtomicAdd(&forces[3 * i + 2], -fzv);
    unsafeAtomicAdd(&forces[3 * j + 0],  fxv);
    unsafeAtomicAdd(&forces[3 * j + 1],  fyv);
    unsafeAtomicAdd(&forces[3 * j + 2],  fzv);
}

// ---------------- launcher ----------------

extern "C" void kernel_launch(void* const* d_in, const int* in_sizes, int n_in,
                              void* d_out, int out_size, void* d_ws, size_t ws_size,
                              hipStream_t stream) {
    const float* positions      = (const float*)d_in[0];
    const float* density_table  = (const float*)d_in[1];
    const float* density_deriv  = (const float*)d_in[2];
    const float* pair_deriv     = (const float*)d_in[3];
    const float* embed_deriv    = (const float*)d_in[4];
    const float* embed_rho_min  = (const float*)d_in[5];
    const float* embed_inv_drho = (const float*)d_in[6];
    const int*   atom_types     = (const int*)d_in[7];
    const int*   edge_i         = (const int*)d_in[8];
    const int*   edge_j         = (const int*)d_in[9];

    const int E     = in_sizes[5];
    const int N     = in_sizes[7];
    const int P     = in_sizes[8];
    const int n_r   = in_sizes[1] / E;
    const int n_rho = in_sizes[4] / E;

    const double R_MAX_d = 6.0;
    const double EPS_d   = 1e-7;
    const float inv_dr    = (float)((double)(n_r - 1) / R_MAX_d);
    const float rclip     = (float)(R_MAX_d * (1.0 - EPS_d));
    const float one_m_eps = (float)(1.0 - EPS_d);

    float* forces = (float*)d_out;

    const int NB = (N + BSZ - 1) >> SHIFT;
    const size_t Npad = ((size_t)N + 3) & ~(size_t)3;

    // ws layout: counts | base | cur | dF | partials (NB*8*3072 f) | recs (2P u32)
    char* wp = (char*)d_ws;
    int* counts = (int*)wp;  wp += NBPAD * sizeof(int);
    int* base   = (int*)wp;  wp += NBPAD * sizeof(int);
    int* cur    = (int*)wp;  wp += NBPAD * sizeof(int);
    wp = (char*)(((uintptr_t)wp + 255) & ~(uintptr_t)255);
    float* dF = (float*)wp;  wp += Npad * sizeof(float);
    float* partials = (float*)wp; wp += (size_t)NB * SSTRIPS * 3 * BSZ * sizeof(float);
    unsigned* recs = (unsigned*)wp; wp += 2 * (size_t)P * sizeof(unsigned);
    const size_t need = (size_t)(wp - (char*)d_ws);

    const int pair_blocks = (P + BLK - 1) / BLK;
    const int atom_blocks = (N + BLK - 1) / BLK;

    if (need > ws_size || NB > NBPAD || N >= (1 << 20)) {
        // fallback: direct agent-atomic path
        float* rho_f = (float*)d_ws;
        eam_zero_rho_forces<<<(3 * N + BLK - 1) / BLK, BLK, 0, stream>>>(rho_f, forces, N);
        eam_density_direct<<<pair_blocks, BLK, 0, stream>>>(
            edge_i, edge_j, atom_types, positions,
            density_table, n_r, inv_dr, rclip, rho_f, P);
        eam_force_direct<<<pair_blocks, BLK, 0, stream>>>(
            edge_i, edge_j, atom_types, positions,
            density_deriv, pair_deriv, rho_f,
            embed_deriv, embed_rho_min, embed_inv_drho,
            n_r, n_rho, E, inv_dr, rclip, one_m_eps, forces, P);
        return;
    }

    eam_zero_meta<<<1, NBPAD, 0, stream>>>(counts);
    eam_count<<<512, BLK, 0, stream>>>(edge_i, edge_j, P, counts);
    eam_scan<<<1, NBPAD, 0, stream>>>(counts, base, cur);

    eam_bin<<<(P + PPB_B - 1) / PPB_B, BLK, 0, stream>>>(
        edge_i, edge_j, P, cur, recs);

    eam_acc_rho<<<NB * SSTRIPS, BLK, 0, stream>>>(
        recs, base, counts, positions, atom_types,
        density_table, n_r, inv_dr, rclip, partials, N);

    eam_reduce_rho_embed<<<atom_blocks, BLK, 0, stream>>>(
        partials, atom_types, embed_deriv, embed_rho_min, embed_inv_drho,
        n_rho, one_m_eps, dF, N);

    eam_acc_force<<<NB * SSTRIPS, BLK, 0, stream>>>(
        recs, base, counts, positions, atom_types, dF,
        density_deriv, pair_deriv,
        n_r, E, inv_dr, rclip, partials, N);

    eam_reduce_force<<<(3 * N + BLK - 1) / BLK, BLK, 0, stream>>>(
        partials, forces, N);
}

// Round 10
// 432.539 us; speedup vs baseline: 5.8430x; 1.1374x over previous
//
#include <hip/hip_runtime.h>
#include <stdint.h>

// EAM force via index-only CSR binning + single-float4 gathers.
//
// HW model: (r3-r7) global fp32 atomics = ~32B fabric transaction, ~20.5G/s
// chip-wide, invariant to everything -> use none. (r9) acc kernels are
// scattered-gather line-request bound (~1 line-req/cy/CU): 5 scattered dword
// gathers per record = ~5 TA reqs. Fix: ONE aligned float4 gather per record:
//   pos4t[n] = (x,y,z, type_bits)            for the rho pass
//   pos4f[n] = (x,y,z, dF with type in 2 LSBs) for the force pass
// dF 2-LSB packing = <=2ulp perturbation (~1e-7 rel) - negligible vs 0.086
// threshold margin. All other math bitwise-identical to the reference.

#define BLK     256
#define SHIFT   10
#define BSZ     1024
#define NBPAD   256
#define SSTRIPS 16
#define PPB_B   4096   // pairs per bin block

__device__ __forceinline__ float interp_row(const float* __restrict__ row,
                                            int i0, int i1, float fr) {
    float a = row[i0];
    float b = row[i1];
    return a + fr * (b - a);
}

__device__ __forceinline__ float embed_dF_f(float rho, int t,
                                            const float* __restrict__ embed_tab,
                                            const float* __restrict__ rho_min_t,
                                            const float* __restrict__ inv_drho_t,
                                            int n_rho, float one_m_eps) {
    float rmin = rho_min_t[t];
    float invd = inv_drho_t[t];
    float hi = rmin + (float)(n_rho - 1) / invd * one_m_eps;
    float rc = fminf(fmaxf(rho, rmin), hi);
    float g  = (rc - rmin) * invd;
    int  g0  = (int)g;
    g0 = g0 < 0 ? 0 : (g0 > n_rho - 2 ? n_rho - 2 : g0);
    float gfr = g - (float)g0;
    const float* row = embed_tab + (size_t)t * n_rho;
    float e0 = row[g0];
    float e1 = row[g0 + 1];
    return e0 + gfr * (e1 - e0);
}

__device__ __forceinline__ void geom_own(
    float xo, float yo, float zo,
    float xw, float yw, float zw,
    float inv_dr, float rclip, int n_r,
    float& dx, float& dy, float& dz, float& r,
    int& i0, int& i1, float& fr)
{
#pragma clang fp contract(off)
    dx = xo - xw; dy = yo - yw; dz = zo - zw;
    float s = dx * dx;
    s = s + dy * dy;
    s = s + dz * dz;
    s = s + 1e-12f;
    r = sqrtf(s);
    float rc = fminf(fmaxf(r, 0.0f), rclip);
    float f  = rc * inv_dr;
    i0 = (int)f;
    fr = f - (float)i0;
    i1 = min(i0 + 1, n_r - 1);
}

// ---------------- meta ----------------

__global__ void eam_zero_meta(int* __restrict__ counts) {
    counts[threadIdx.x] = 0;
}

__global__ void eam_count(const int* __restrict__ ei, const int* __restrict__ ej,
                          int P, int* __restrict__ counts)
{
    __shared__ int cnt[NBPAD];
    for (int k = threadIdx.x; k < NBPAD; k += BLK) cnt[k] = 0;
    __syncthreads();
    for (int p = blockIdx.x * BLK + threadIdx.x; p < P; p += gridDim.x * BLK) {
        atomicAdd(&cnt[((unsigned)ei[p]) >> SHIFT], 1);
        atomicAdd(&cnt[((unsigned)ej[p]) >> SHIFT], 1);
    }
    __syncthreads();
    for (int k = threadIdx.x; k < NBPAD; k += BLK)
        if (cnt[k]) atomicAdd(&counts[k], cnt[k]);
}

__global__ void eam_scan(const int* __restrict__ counts,
                         int* __restrict__ base, int* __restrict__ cur)
{
    __shared__ int s[NBPAD];
    int t = threadIdx.x;
    int c = counts[t];
    s[t] = c;
    __syncthreads();
    for (int d = 1; d < NBPAD; d <<= 1) {
        int v = (t >= d) ? s[t - d] : 0;
        __syncthreads();
        s[t] += v;
        __syncthreads();
    }
    base[t] = s[t] - c;
    cur[t]  = s[t] - c;
}

// ---------------- pos4t build ----------------

__global__ void eam_build_pos4t(const float* __restrict__ pos,
                                const int* __restrict__ types,
                                float4* __restrict__ pos4t, int N)
{
    int n = blockIdx.x * blockDim.x + threadIdx.x;
    if (n >= N) return;
    float4 v;
    v.x = pos[3 * n + 0];
    v.y = pos[3 * n + 1];
    v.z = pos[3 * n + 2];
    v.w = __int_as_float(types[n]);
    pos4t[n] = v;
}

// ---------------- bin: directed index records ----------------

__global__ __launch_bounds__(BLK) void eam_bin(
    const int* __restrict__ ei, const int* __restrict__ ej, int P,
    int* __restrict__ cur_glob, unsigned* __restrict__ recs)
{
    __shared__ int cnt[NBPAD], off[NBPAD], curs[NBPAD], gb[NBPAD], sc[NBPAD];
    __shared__ unsigned sR[2 * PPB_B];
    __shared__ unsigned char sB[2 * PPB_B];
    const int tid = threadIdx.x;
    const long long p0 = (long long)blockIdx.x * PPB_B;
    const int pend = (int)((p0 + PPB_B < (long long)P) ? p0 + PPB_B : (long long)P);

    for (int k = tid; k < NBPAD; k += BLK) cnt[k] = 0;
    __syncthreads();

    for (int p = (int)p0 + tid; p < pend; p += BLK) {
        atomicAdd(&cnt[((unsigned)ei[p]) >> SHIFT], 1);
        atomicAdd(&cnt[((unsigned)ej[p]) >> SHIFT], 1);
    }
    __syncthreads();

    int c = cnt[tid];
    sc[tid] = c;
    __syncthreads();
    for (int d = 1; d < NBPAD; d <<= 1) {
        int v = (tid >= d) ? sc[tid - d] : 0;
        __syncthreads();
        sc[tid] += v;
        __syncthreads();
    }
    off[tid] = sc[tid] - c;
    curs[tid] = off[tid];
    if (c > 0) gb[tid] = atomicAdd(&cur_glob[tid], c);
    __syncthreads();

    for (int p = (int)p0 + tid; p < pend; p += BLK) {
        unsigned i = (unsigned)ei[p];
        unsigned j = (unsigned)ej[p];
        int bi = i >> SHIFT;
        int sl = atomicAdd(&curs[bi], 1);
        sR[sl] = j | ((i & (BSZ - 1)) << 20) | (1u << 30);  // owner=i
        sB[sl] = (unsigned char)bi;
        int bj = j >> SHIFT;
        sl = atomicAdd(&curs[bj], 1);
        sR[sl] = i | ((j & (BSZ - 1)) << 20);               // owner=j
        sB[sl] = (unsigned char)bj;
    }
    __syncthreads();

    int total = off[NBPAD - 1] + cnt[NBPAD - 1];
    for (int q = tid; q < total; q += BLK) {
        int b = sB[q];
        int dst = gb[b] + (q - off[b]);
        recs[dst] = sR[q];
    }
}

// ---------------- acc rho ----------------

__global__ __launch_bounds__(BLK) void eam_acc_rho(
    const unsigned* __restrict__ recs,
    const int* __restrict__ base, const int* __restrict__ counts,
    const float4* __restrict__ pos4t,
    const float* __restrict__ dens_tab, int n_r, float inv_dr, float rclip,
    float* __restrict__ partial, int N)
{
    __shared__ float4 sown[BSZ];
    __shared__ float slab[BSZ];
    const int tid = threadIdx.x;
    const int b = blockIdx.x / SSTRIPS;
    const int s = blockIdx.x % SSTRIPS;
    const int abase = b << SHIFT;

    for (int k = tid; k < BSZ; k += BLK) {
        int a = abase + k;
        sown[k] = (a < N) ? pos4t[a] : make_float4(0.f, 0.f, 0.f, 0.f);
        slab[k] = 0.f;
    }
    __syncthreads();

    int cb = counts[b];
    int e0 = base[b] + (int)(((long long)cb * s) / SSTRIPS);
    int e1 = base[b] + (int)(((long long)cb * (s + 1)) / SSTRIPS);

    for (int q = e0 + tid; q < e1; q += BLK) {
        unsigned rec = recs[q];
        int other = rec & 0xFFFFF;
        int low = (rec >> 20) & (BSZ - 1);
        float4 w = sown[low];
        float4 o = pos4t[other];                 // ONE scattered gather
        float dx, dy, dz, r, fr; int i0, i1;
        geom_own(o.x, o.y, o.z, w.x, w.y, w.z, inv_dr, rclip, n_r,
                 dx, dy, dz, r, i0, i1, fr);
        int t_oth = __float_as_int(o.w);
        float v = interp_row(dens_tab + (size_t)t_oth * n_r, i0, i1, fr);
        atomicAdd(&slab[low], v);
    }
    __syncthreads();

    float* out = partial + ((size_t)(b * SSTRIPS + s) << SHIFT);
    for (int k = tid; k < BSZ; k += BLK) out[k] = slab[k];
}

// rho = sum strips; dF = F'(rho); pos4f = (x,y,z, dF with type in 2 LSBs)
__global__ void eam_reduce_rho_embed_pack(
    const float* __restrict__ partial, const float* __restrict__ pos,
    const int* __restrict__ types,
    const float* __restrict__ embed_tab,
    const float* __restrict__ rho_min_t, const float* __restrict__ inv_drho_t,
    int n_rho, float one_m_eps, float4* __restrict__ pos4f, int N)
{
    int n = blockIdx.x * blockDim.x + threadIdx.x;
    if (n >= N) return;
    int b = n >> SHIFT;
    int low = n & (BSZ - 1);
    float rho = 0.f;
#pragma unroll
    for (int s = 0; s < SSTRIPS; ++s)
        rho += partial[((size_t)(b * SSTRIPS + s) << SHIFT) + low];
    int t = types[n];
    float dF = embed_dF_f(rho, t, embed_tab, rho_min_t, inv_drho_t,
                          n_rho, one_m_eps);
    unsigned u = (__float_as_uint(dF) & ~3u) | ((unsigned)t & 3u);
    float4 v;
    v.x = pos[3 * n + 0];
    v.y = pos[3 * n + 1];
    v.z = pos[3 * n + 2];
    v.w = __uint_as_float(u);
    pos4f[n] = v;
}

// ---------------- acc force ----------------

__global__ __launch_bounds__(BLK) void eam_acc_force(
    const unsigned* __restrict__ recs,
    const int* __restrict__ base, const int* __restrict__ counts,
    const float4* __restrict__ pos4f,
    const float* __restrict__ dens_deriv_tab,
    const float* __restrict__ pair_deriv_tab,
    int n_r, int E, float inv_dr, float rclip,
    float* __restrict__ partial, int N)
{
    __shared__ float4 sown[BSZ];
    __shared__ float slab[3 * BSZ];
    const int tid = threadIdx.x;
    const int b = blockIdx.x / SSTRIPS;
    const int s = blockIdx.x % SSTRIPS;
    const int abase = b << SHIFT;

    for (int k = tid; k < BSZ; k += BLK) {
        int a = abase + k;
        sown[k] = (a < N) ? pos4f[a] : make_float4(0.f, 0.f, 0.f, 0.f);
    }
    for (int k = tid; k < 3 * BSZ; k += BLK) slab[k] = 0.f;
    __syncthreads();

    int cb = counts[b];
    int e0 = base[b] + (int)(((long long)cb * s) / SSTRIPS);
    int e1 = base[b] + (int)(((long long)cb * (s + 1)) / SSTRIPS);

    for (int q = e0 + tid; q < e1; q += BLK) {
        unsigned rec = recs[q];
        int other  = rec & 0xFFFFF;
        int low    = (rec >> 20) & (BSZ - 1);
        int orient = (rec >> 30) & 1;

        float4 w = sown[low];
        int   t_own  = (int)(__float_as_uint(w.w) & 3u);
        float dF_own = w.w;

        float4 o = pos4f[other];                 // ONE scattered gather
        int   t_oth  = (int)(__float_as_uint(o.w) & 3u);
        float dF_oth = o.w;

        float dx, dy, dz, r, fr; int i0, i1;
        geom_own(o.x, o.y, o.z, w.x, w.y, w.z, inv_dr, rclip, n_r,
                 dx, dy, dz, r, i0, i1, fr);

        float ddens_oth = interp_row(dens_deriv_tab + (size_t)t_oth * n_r, i0, i1, fr);
        float ddens_own = interp_row(dens_deriv_tab + (size_t)t_own * n_r, i0, i1, fr);
        int prow = orient ? (t_own * E + t_oth) : (t_oth * E + t_own);
        float dphi = interp_row(pair_deriv_tab + (size_t)prow * n_r, i0, i1, fr);

        float coeff = dF_own * ddens_oth + dF_oth * ddens_own + dphi;

        float fx = -(coeff * (dx / r));
        float fy = -(coeff * (dy / r));
        float fz = -(coeff * (dz / r));

        atomicAdd(&slab[low * 3 + 0], fx);
        atomicAdd(&slab[low * 3 + 1], fy);
        atomicAdd(&slab[low * 3 + 2], fz);
    }
    __syncthreads();

    float* out = partial + (size_t)(b * SSTRIPS + s) * (3 * BSZ);
    for (int k = tid; k < 3 * BSZ; k += BLK) out[k] = slab[k];
}

__global__ void eam_reduce_force(const float* __restrict__ partial,
                                 float* __restrict__ forces, int N)
{
    int idx = blockIdx.x * blockDim.x + threadIdx.x;
    if (idx >= 3 * N) return;
    int a = idx / 3;
    int comp = idx - 3 * a;
    int b = a >> SHIFT;
    int low = a & (BSZ - 1);
    float s = 0.f;
#pragma unroll
    for (int k = 0; k < SSTRIPS; ++k)
        s += partial[(size_t)(b * SSTRIPS + k) * (3 * BSZ) + low * 3 + comp];
    forces[idx] = s;
}

// ---------------- fallback: direct agent-atomic path ----------------

__device__ __forceinline__ void pair_geom(
    const float* __restrict__ pos, int i, int j,
    float inv_dr, float rclip,
    float& dx, float& dy, float& dz, float& r,
    int& i0, int& i1, float& fr, int n_r)
{
#pragma clang fp contract(off)
    float xi = pos[3 * i + 0], yi = pos[3 * i + 1], zi = pos[3 * i + 2];
    float xj = pos[3 * j + 0], yj = pos[3 * j + 1], zj = pos[3 * j + 2];
    dx = xj - xi; dy = yj - yi; dz = zj - zi;
    float s = dx * dx;
    s = s + dy * dy;
    s = s + dz * dz;
    s = s + 1e-12f;
    r = sqrtf(s);
    float rc = fminf(fmaxf(r, 0.0f), rclip);
    float f  = rc * inv_dr;
    i0 = (int)f;
    fr = f - (float)i0;
    i1 = min(i0 + 1, n_r - 1);
}

__global__ void eam_zero_rho_forces(float* __restrict__ rho,
                                    float* __restrict__ forces, int N) {
    int idx = blockIdx.x * blockDim.x + threadIdx.x;
    if (idx < N) rho[idx] = 0.0f;
    if (idx < 3 * N) forces[idx] = 0.0f;
}

__global__ void eam_density_direct(
    const int* __restrict__ ei, const int* __restrict__ ej,
    const int* __restrict__ types, const float* __restrict__ pos,
    const float* __restrict__ dens_tab, int n_r, float inv_dr, float rclip,
    float* __restrict__ rho, int P)
{
    int p = blockIdx.x * blockDim.x + threadIdx.x;
    if (p >= P) return;
    int i = ei[p], j = ej[p];
    float dx, dy, dz, r, fr; int i0, i1;
    pair_geom(pos, i, j, inv_dr, rclip, dx, dy, dz, r, i0, i1, fr, n_r);
    int ti = types[i], tj = types[j];
    unsafeAtomicAdd(&rho[i], interp_row(dens_tab + (size_t)tj * n_r, i0, i1, fr));
    unsafeAtomicAdd(&rho[j], interp_row(dens_tab + (size_t)ti * n_r, i0, i1, fr));
}

__global__ void eam_force_direct(
    const int* __restrict__ ei, const int* __restrict__ ej,
    const int* __restrict__ types, const float* __restrict__ pos,
    const float* __restrict__ dens_deriv_tab,
    const float* __restrict__ pair_deriv_tab,
    const float* __restrict__ rho,
    const float* __restrict__ embed_tab,
    const float* __restrict__ rho_min_t, const float* __restrict__ inv_drho_t,
    int n_r, int n_rho, int E, float inv_dr, float rclip, float one_m_eps,
    float* __restrict__ forces, int P)
{
    int p = blockIdx.x * blockDim.x + threadIdx.x;
    if (p >= P) return;
    int i = ei[p], j = ej[p];
    float dx, dy, dz, r, fr; int i0, i1;
    pair_geom(pos, i, j, inv_dr, rclip, dx, dy, dz, r, i0, i1, fr, n_r);
    int ti = types[i], tj = types[j];
    float ddens_j = interp_row(dens_deriv_tab + (size_t)tj * n_r, i0, i1, fr);
    float ddens_i = interp_row(dens_deriv_tab + (size_t)ti * n_r, i0, i1, fr);
    float dphi    = interp_row(pair_deriv_tab + ((size_t)ti * E + tj) * n_r, i0, i1, fr);
    float dFi = embed_dF_f(rho[i], ti, embed_tab, rho_min_t, inv_drho_t, n_rho, one_m_eps);
    float dFj = embed_dF_f(rho[j], tj, embed_tab, rho_min_t, inv_drho_t, n_rho, one_m_eps);
    float coeff = dFi * ddens_j + dFj * ddens_i + dphi;
    float fxv = coeff * (dx / r), fyv = coeff * (dy / r), fzv = coeff * (dz / r);
    unsafeAtomicAdd(&forces[3 * i + 0], -fxv);
    unsafeAtomicAdd(&forces[3 * i + 1], -fyv);
    unsafeAtomicAdd(&forces[3 * i + 2], -fzv);
    unsafeAtomicAdd(&forces[3 * j + 0],  fxv);
    unsafeAtomicAdd(&forces[3 * j + 1],  fyv);
    unsafeAtomicAdd(&forces[3 * j + 2],  fzv);
}

// ---------------- launcher ----------------

extern "C" void kernel_launch(void* const* d_in, const int* in_sizes, int n_in,
                              void* d_out, int out_size, void* d_ws, size_t ws_size,
                              hipStream_t stream) {
    const float* positions      = (const float*)d_in[0];
    const float* density_table  = (const float*)d_in[1];
    const float* density_deriv  = (const float*)d_in[2];
    const float* pair_deriv     = (const float*)d_in[3];
    const float* embed_deriv    = (const float*)d_in[4];
    const float* embed_rho_min  = (const float*)d_in[5];
    const float* embed_inv_drho = (const float*)d_in[6];
    const int*   atom_types     = (const int*)d_in[7];
    const int*   edge_i         = (const int*)d_in[8];
    const int*   edge_j         = (const int*)d_in[9];

    const int E     = in_sizes[5];
    const int N     = in_sizes[7];
    const int P     = in_sizes[8];
    const int n_r   = in_sizes[1] / E;
    const int n_rho = in_sizes[4] / E;

    const double R_MAX_d = 6.0;
    const double EPS_d   = 1e-7;
    const float inv_dr    = (float)((double)(n_r - 1) / R_MAX_d);
    const float rclip     = (float)(R_MAX_d * (1.0 - EPS_d));
    const float one_m_eps = (float)(1.0 - EPS_d);

    float* forces = (float*)d_out;

    const int NB = (N + BSZ - 1) >> SHIFT;

    // ws: counts|base|cur | pos4t[N] | pos4f[N] | partials | recs
    char* wp = (char*)d_ws;
    int* counts = (int*)wp;  wp += NBPAD * sizeof(int);
    int* base   = (int*)wp;  wp += NBPAD * sizeof(int);
    int* cur    = (int*)wp;  wp += NBPAD * sizeof(int);
    wp = (char*)(((uintptr_t)wp + 255) & ~(uintptr_t)255);
    float4* pos4t = (float4*)wp; wp += (size_t)N * sizeof(float4);
    float4* pos4f = (float4*)wp; wp += (size_t)N * sizeof(float4);
    float* partials = (float*)wp; wp += (size_t)NB * SSTRIPS * 3 * BSZ * sizeof(float);
    unsigned* recs = (unsigned*)wp; wp += 2 * (size_t)P * sizeof(unsigned);
    const size_t need = (size_t)(wp - (char*)d_ws);

    const int pair_blocks = (P + BLK - 1) / BLK;
    const int atom_blocks = (N + BLK - 1) / BLK;

    if (need > ws_size || NB > NBPAD || N >= (1 << 20) || E > 4) {
        float* rho_f = (float*)d_ws;
        eam_zero_rho_forces<<<(3 * N + BLK - 1) / BLK, BLK, 0, stream>>>(rho_f, forces, N);
        eam_density_direct<<<pair_blocks, BLK, 0, stream>>>(
            edge_i, edge_j, atom_types, positions,
            density_table, n_r, inv_dr, rclip, rho_f, P);
        eam_force_direct<<<pair_blocks, BLK, 0, stream>>>(
            edge_i, edge_j, atom_types, positions,
            density_deriv, pair_deriv, rho_f,
            embed_deriv, embed_rho_min, embed_inv_drho,
            n_r, n_rho, E, inv_dr, rclip, one_m_eps, forces, P);
        return;
    }

    eam_zero_meta<<<1, NBPAD, 0, stream>>>(counts);
    eam_count<<<512, BLK, 0, stream>>>(edge_i, edge_j, P, counts);
    eam_scan<<<1, NBPAD, 0, stream>>>(counts, base, cur);
    eam_build_pos4t<<<atom_blocks, BLK, 0, stream>>>(positions, atom_types, pos4t, N);

    eam_bin<<<(P + PPB_B - 1) / PPB_B, BLK, 0, stream>>>(
        edge_i, edge_j, P, cur, recs);

    eam_acc_rho<<<NB * SSTRIPS, BLK, 0, stream>>>(
        recs, base, counts, pos4t,
        density_table, n_r, inv_dr, rclip, partials, N);

    eam_reduce_rho_embed_pack<<<atom_blocks, BLK, 0, stream>>>(
        partials, positions, atom_types,
        embed_deriv, embed_rho_min, embed_inv_drho,
        n_rho, one_m_eps, pos4f, N);

    eam_acc_force<<<NB * SSTRIPS, BLK, 0, stream>>>(
        recs, base, counts, pos4f,
        density_deriv, pair_deriv,
        n_r, E, inv_dr, rclip, partials, N);

    eam_reduce_force<<<(3 * N + BLK - 1) / BLK, BLK, 0, stream>>>(
        partials, forces, N);
}